// Round 1
// baseline (9017.233 us; speedup 1.0000x reference)
//
#include <hip/hip_runtime.h>
#include <hip/hip_bf16.h>

// ---------------------------------------------------------------------------
// GCN graph classification: 3x GCNConv(128->128) + mean/max pool + FC(256->10)
// Round 0: correctness-first fp32 implementation.
// ---------------------------------------------------------------------------

__global__ __launch_bounds__(256) void deg_kernel(const int* __restrict__ dst,
                                                  float* __restrict__ deg, int ne) {
    int e = blockIdx.x * 256 + threadIdx.x;
    if (e < ne) atomicAdd(&deg[dst[e]], 1.0f);
}

__global__ __launch_bounds__(256) void dinv_kernel(float* __restrict__ deg, int n) {
    int i = blockIdx.x * 256 + threadIdx.x;
    if (i < n) deg[i] = 1.0f / sqrtf(deg[i] + 1.0f);   // exact sqrt, not v_rsq approx
}

// Y[n,128] = X[n,128] @ W[128,128].  16 rows/block, 256 threads,
// each thread computes 8 contiguous output cols of one row. W staged in LDS.
__global__ __launch_bounds__(256) void gemm_nn(const float* __restrict__ X,
                                               const float* __restrict__ W,
                                               float* __restrict__ Y, int n) {
    __shared__ float Ws[128 * 128];   // 64 KiB
    int t = threadIdx.x;
    for (int i = t * 4; i < 128 * 128; i += 256 * 4)
        *(float4*)&Ws[i] = *(const float4*)&W[i];
    __syncthreads();

    int row = blockIdx.x * 16 + (t >> 4);
    if (row >= n) return;
    int cc = (t & 15) * 8;
    float acc[8] = {0.f, 0.f, 0.f, 0.f, 0.f, 0.f, 0.f, 0.f};
    const float* xr = X + (size_t)row * 128;
    for (int k = 0; k < 128; ++k) {
        float xv = xr[k];
        const float* wr = &Ws[k * 128 + cc];
#pragma unroll
        for (int j = 0; j < 8; ++j) acc[j] += xv * wr[j];
    }
    float* yr = Y + (size_t)row * 128 + cc;
#pragma unroll
    for (int j = 0; j < 8; ++j) yr[j] = acc[j];
}

// For each edge e: AGG[dst[e], :] += T[src[e], :] * dinv[src]*dinv[dst]
// 32 threads per edge, float4 per thread, scalar f32 atomics.
__global__ __launch_bounds__(256) void scatter_add(const float* __restrict__ T,
                                                   const int* __restrict__ src,
                                                   const int* __restrict__ dst,
                                                   const float* __restrict__ dinv,
                                                   float* __restrict__ AGG, int ne) {
    long long idx = (long long)blockIdx.x * 256 + threadIdx.x;
    int e = (int)(idx >> 5);
    if (e >= ne) return;
    int lane = (int)(idx & 31);
    int s = src[e], d = dst[e];
    float nrm = dinv[s] * dinv[d];
    float4 v = *(const float4*)&T[(size_t)s * 128 + lane * 4];
    float* o = &AGG[(size_t)d * 128 + lane * 4];
    atomicAdd(o + 0, v.x * nrm);
    atomicAdd(o + 1, v.y * nrm);
    atomicAdd(o + 2, v.z * nrm);
    atomicAdd(o + 3, v.w * nrm);
}

// AGG = relu(AGG + T * dinv^2 + b)
__global__ __launch_bounds__(256) void finalize_kernel(float* __restrict__ AGG,
                                                       const float* __restrict__ T,
                                                       const float* __restrict__ dinv,
                                                       const float* __restrict__ b, int n) {
    long long idx = (long long)blockIdx.x * 256 + threadIdx.x;   // n*32 float4 chunks
    if (idx >= (long long)n * 32) return;
    int node = (int)(idx >> 5);
    int f4 = (int)(idx & 31) * 4;
    float di = dinv[node];
    float sl = di * di;
    float4 a = *(float4*)&AGG[(size_t)node * 128 + f4];
    float4 t = *(const float4*)&T[(size_t)node * 128 + f4];
    float4 bb = *(const float4*)&b[f4];
    a.x = fmaxf(fmaf(t.x, sl, a.x) + bb.x, 0.f);
    a.y = fmaxf(fmaf(t.y, sl, a.y) + bb.y, 0.f);
    a.z = fmaxf(fmaf(t.z, sl, a.z) + bb.z, 0.f);
    a.w = fmaxf(fmaf(t.w, sl, a.w) + bb.w, 0.f);
    *(float4*)&AGG[(size_t)node * 128 + f4] = a;
}

// Per-graph sum (atomicAdd), max (int-compare atomicMax, valid since h >= 0),
// and node counts.
__global__ __launch_bounds__(256) void pool_kernel(const float* __restrict__ H,
                                                   const int* __restrict__ batch,
                                                   float* __restrict__ gsum,
                                                   int* __restrict__ gmax,
                                                   float* __restrict__ gcnt, int n) {
    long long idx = (long long)blockIdx.x * 256 + threadIdx.x;   // n*32 chunks
    if (idx >= (long long)n * 32) return;
    int node = (int)(idx >> 5);
    int f4 = (int)(idx & 31) * 4;
    int g = batch[node];
    float4 h = *(const float4*)&H[(size_t)node * 128 + f4];
    atomicAdd(&gsum[(size_t)g * 128 + f4 + 0], h.x);
    atomicAdd(&gsum[(size_t)g * 128 + f4 + 1], h.y);
    atomicAdd(&gsum[(size_t)g * 128 + f4 + 2], h.z);
    atomicAdd(&gsum[(size_t)g * 128 + f4 + 3], h.w);
    atomicMax(&gmax[(size_t)g * 128 + f4 + 0], __float_as_int(h.x));
    atomicMax(&gmax[(size_t)g * 128 + f4 + 1], __float_as_int(h.y));
    atomicMax(&gmax[(size_t)g * 128 + f4 + 2], __float_as_int(h.z));
    atomicMax(&gmax[(size_t)g * 128 + f4 + 3], __float_as_int(h.w));
    if ((idx & 31) == 0) atomicAdd(&gcnt[g], 1.0f);
}

// out[g, c] = concat(mean, max)[g, :] @ fc_W + fc_b
__global__ __launch_bounds__(64) void fc_kernel(const float* __restrict__ gsum,
                                                const int* __restrict__ gmax,
                                                const float* __restrict__ gcnt,
                                                const float* __restrict__ fcW,
                                                const float* __restrict__ fcb,
                                                float* __restrict__ out, int C) {
    int g = blockIdx.x;
    __shared__ float pooled[256];
    int t = threadIdx.x;
    float cnt = fmaxf(gcnt[g], 1.0f);
    for (int k = t; k < 128; k += 64) {
        pooled[k] = gsum[(size_t)g * 128 + k] / cnt;
        pooled[128 + k] = __int_as_float(gmax[(size_t)g * 128 + k]);
    }
    __syncthreads();
    if (t < C) {
        float acc = fcb[t];
        for (int k = 0; k < 256; ++k) acc = fmaf(pooled[k], fcW[k * C + t], acc);
        out[(size_t)g * C + t] = acc;
    }
}

extern "C" void kernel_launch(void* const* d_in, const int* in_sizes, int n_in,
                              void* d_out, int out_size, void* d_ws, size_t ws_size,
                              hipStream_t stream) {
    const float* x     = (const float*)d_in[0];
    const int*   ei    = (const int*)d_in[1];
    const int*   batch = (const int*)d_in[2];
    const float* W1    = (const float*)d_in[3];
    const float* b1    = (const float*)d_in[4];
    const float* W2    = (const float*)d_in[5];
    const float* b2    = (const float*)d_in[6];
    const float* W3    = (const float*)d_in[7];
    const float* b3    = (const float*)d_in[8];
    const float* fcW   = (const float*)d_in[9];
    const float* fcb   = (const float*)d_in[10];

    const int N = in_sizes[0] / 128;
    const int E = in_sizes[1] / 2;
    const int C = in_sizes[10];
    const int G = out_size / C;
    float* out = (float*)d_out;

    float* A    = (float*)d_ws;                   // cur features / agg  [N*128]
    float* B    = A + (size_t)N * 128;            // transform output    [N*128]
    float* dinv = B + (size_t)N * 128;            // deg -> dinv         [N]
    float* gsum = dinv + N;                       // [G*128]
    float* gmaxf = gsum + (size_t)G * 128;        // [G*128] (int view)
    int*   gmax = (int*)gmaxf;
    float* gcnt = gmaxf + (size_t)G * 128;        // [G]

    const int* src = ei;
    const int* dst = ei + E;

    // degrees -> dinv
    hipMemsetAsync(dinv, 0, (size_t)N * sizeof(float), stream);
    deg_kernel<<<(E + 255) / 256, 256, 0, stream>>>(dst, dinv, E);
    dinv_kernel<<<(N + 255) / 256, 256, 0, stream>>>(dinv, N);

    const long long eThreads = (long long)E * 32;
    const long long nThreads = (long long)N * 32;

    auto layer = [&](const float* cur, const float* W, const float* b) {
        gemm_nn<<<(N + 15) / 16, 256, 0, stream>>>(cur, W, B, N);
        hipMemsetAsync(A, 0, (size_t)N * 128 * sizeof(float), stream);
        scatter_add<<<(int)((eThreads + 255) / 256), 256, 0, stream>>>(B, src, dst, dinv, A, E);
        finalize_kernel<<<(int)((nThreads + 255) / 256), 256, 0, stream>>>(A, B, dinv, b, N);
    };
    layer(x, W1, b1);
    layer(A, W2, b2);
    layer(A, W3, b3);

    // pooling + FC
    hipMemsetAsync(gsum, 0, (size_t)G * 257 * sizeof(float), stream);
    pool_kernel<<<(int)((nThreads + 255) / 256), 256, 0, stream>>>(A, batch, gsum, gmax, gcnt, N);
    fc_kernel<<<G, 64, 0, stream>>>(gsum, gmax, gcnt, fcW, fcb, out, C);
}

// Round 2
// 1113.362 us; speedup vs baseline: 8.0991x; 8.0991x over previous
//
#include <hip/hip_runtime.h>
#include <hip/hip_bf16.h>

// ---------------------------------------------------------------------------
// GCN graph classification: 3x GCNConv(128->128) + mean/max pool + FC(256->10)
// Round 1: replace atomic scatter with CSR(dst) build + register-gather
//          aggregation; segmented (sorted-batch) pooling, no atomics.
// ---------------------------------------------------------------------------

__global__ __launch_bounds__(256) void hist_kernel(const int* __restrict__ dst,
                                                   int* __restrict__ counts, int ne) {
    int e = blockIdx.x * 256 + threadIdx.x;
    if (e < ne) atomicAdd(&counts[dst[e]], 1);
}

// Single-block chunked exclusive scan of counts -> row_ptr/cursor; also dinv.
__global__ __launch_bounds__(1024) void scan_kernel(const int* __restrict__ counts,
                                                    int* __restrict__ row_ptr,
                                                    int* __restrict__ cursor,
                                                    float* __restrict__ dinv, int n) {
    __shared__ int wsum[16];
    int t = threadIdx.x;
    int lane = t & 63, wid = t >> 6;
    int running = 0;
    for (int base = 0; base < n; base += 1024) {
        int i = base + t;
        int v = (i < n) ? counts[i] : 0;
        int sc = v;                       // inclusive wave scan
#pragma unroll
        for (int off = 1; off < 64; off <<= 1) {
            int u = __shfl_up(sc, off, 64);
            if (lane >= off) sc += u;
        }
        if (lane == 63) wsum[wid] = sc;
        __syncthreads();
        if (wid == 0) {
            int w = (lane < 16) ? wsum[lane] : 0;
#pragma unroll
            for (int off = 1; off < 16; off <<= 1) {
                int u = __shfl_up(w, off, 64);
                if (lane >= off) w += u;
            }
            if (lane < 16) wsum[lane] = w;    // inclusive over wave sums
        }
        __syncthreads();
        int wbase = (wid == 0) ? 0 : wsum[wid - 1];
        int excl = running + wbase + (sc - v);
        if (i < n) {
            row_ptr[i] = excl;
            cursor[i]  = excl;
            dinv[i] = 1.0f / sqrtf((float)v + 1.0f);   // exact sqrt
        }
        running += wsum[15];
        __syncthreads();
    }
    if (t == 0) row_ptr[n] = running;
}

__global__ __launch_bounds__(256) void fill_kernel(const int* __restrict__ src,
                                                   const int* __restrict__ dst,
                                                   int* __restrict__ cursor,
                                                   int* __restrict__ csr_src, int ne) {
    int e = blockIdx.x * 256 + threadIdx.x;
    if (e >= ne) return;
    int pos = atomicAdd(&cursor[dst[e]], 1);
    csr_src[pos] = src[e];
}

// Y[n,128] = X[n,128] @ W[128,128]; W staged in LDS (unchanged from R0).
__global__ __launch_bounds__(256) void gemm_nn(const float* __restrict__ X,
                                               const float* __restrict__ W,
                                               float* __restrict__ Y, int n) {
    __shared__ float Ws[128 * 128];
    int t = threadIdx.x;
    for (int i = t * 4; i < 128 * 128; i += 256 * 4)
        *(float4*)&Ws[i] = *(const float4*)&W[i];
    __syncthreads();

    int row = blockIdx.x * 16 + (t >> 4);
    if (row >= n) return;
    int cc = (t & 15) * 8;
    float acc[8] = {0.f, 0.f, 0.f, 0.f, 0.f, 0.f, 0.f, 0.f};
    const float* xr = X + (size_t)row * 128;
    for (int k = 0; k < 128; ++k) {
        float xv = xr[k];
        const float* wr = &Ws[k * 128 + cc];
#pragma unroll
        for (int j = 0; j < 8; ++j) acc[j] += xv * wr[j];
    }
    float* yr = Y + (size_t)row * 128 + cc;
#pragma unroll
    for (int j = 0; j < 8; ++j) yr[j] = acc[j];
}

// A[d,:] = relu( dinv[d] * sum_{e in row d} dinv[src]*T[src,:]
//               + dinv[d]^2 * T[d,:] + b )
// 32 lanes per node (float4 each), register accumulation, one write.
__global__ __launch_bounds__(256) void agg_fused(const float* __restrict__ T,
                                                 const int* __restrict__ row_ptr,
                                                 const int* __restrict__ csr_src,
                                                 const float* __restrict__ dinv,
                                                 const float* __restrict__ b,
                                                 float* __restrict__ A, int n) {
    int node = blockIdx.x * 8 + (threadIdx.x >> 5);
    if (node >= n) return;
    int lane = threadIdx.x & 31;
    int beg = row_ptr[node], end = row_ptr[node + 1];
    float4 acc = {0.f, 0.f, 0.f, 0.f};
    if (beg < end) {
        int s = csr_src[beg];
        for (int e = beg; e < end; ++e) {
            int snext = (e + 1 < end) ? csr_src[e + 1] : 0;  // prefetch index
            float w = dinv[s];
            float4 v = *(const float4*)&T[(size_t)s * 128 + lane * 4];
            acc.x = fmaf(w, v.x, acc.x);
            acc.y = fmaf(w, v.y, acc.y);
            acc.z = fmaf(w, v.z, acc.z);
            acc.w = fmaf(w, v.w, acc.w);
            s = snext;
        }
    }
    float dn = dinv[node];
    float sl = dn * dn;
    float4 tv = *(const float4*)&T[(size_t)node * 128 + lane * 4];
    float4 bb = *(const float4*)&b[lane * 4];
    float4 h;
    h.x = fmaxf(fmaf(acc.x, dn, fmaf(tv.x, sl, bb.x)), 0.f);
    h.y = fmaxf(fmaf(acc.y, dn, fmaf(tv.y, sl, bb.y)), 0.f);
    h.z = fmaxf(fmaf(acc.z, dn, fmaf(tv.z, sl, bb.z)), 0.f);
    h.w = fmaxf(fmaf(acc.w, dn, fmaf(tv.w, sl, bb.w)), 0.f);
    *(float4*)&A[(size_t)node * 128 + lane * 4] = h;
}

__device__ __forceinline__ int lower_bound(const int* __restrict__ a, int n, int key) {
    int lo = 0, hi = n;
    while (lo < hi) {
        int mid = (lo + hi) >> 1;
        if (a[mid] < key) lo = mid + 1; else hi = mid;
    }
    return lo;
}

// Segmented pool over sorted batch: block per graph, thread per feature.
__global__ __launch_bounds__(128) void pool_kernel(const float* __restrict__ H,
                                                   const int* __restrict__ batch,
                                                   float* __restrict__ pooled, int n) {
    int g = blockIdx.x;
    int beg = lower_bound(batch, n, g);
    int end = lower_bound(batch, n, g + 1);
    int f = threadIdx.x;
    float s = 0.f, m = -INFINITY;
    for (int i = beg; i < end; ++i) {
        float v = H[(size_t)i * 128 + f];
        s += v;
        m = fmaxf(m, v);
    }
    float cnt = (float)(end - beg);
    pooled[(size_t)g * 256 + f]       = s / fmaxf(cnt, 1.0f);
    pooled[(size_t)g * 256 + 128 + f] = m;
}

__global__ __launch_bounds__(64) void fc_kernel(const float* __restrict__ pooled,
                                                const float* __restrict__ fcW,
                                                const float* __restrict__ fcb,
                                                float* __restrict__ out, int C) {
    int g = blockIdx.x;
    __shared__ float p[256];
    int t = threadIdx.x;
    for (int k = t; k < 256; k += 64) p[k] = pooled[(size_t)g * 256 + k];
    __syncthreads();
    if (t < C) {
        float acc = fcb[t];
        for (int k = 0; k < 256; ++k) acc = fmaf(p[k], fcW[k * C + t], acc);
        out[(size_t)g * C + t] = acc;
    }
}

extern "C" void kernel_launch(void* const* d_in, const int* in_sizes, int n_in,
                              void* d_out, int out_size, void* d_ws, size_t ws_size,
                              hipStream_t stream) {
    const float* x     = (const float*)d_in[0];
    const int*   ei    = (const int*)d_in[1];
    const int*   batch = (const int*)d_in[2];
    const float* W1    = (const float*)d_in[3];
    const float* b1    = (const float*)d_in[4];
    const float* W2    = (const float*)d_in[5];
    const float* b2    = (const float*)d_in[6];
    const float* W3    = (const float*)d_in[7];
    const float* b3    = (const float*)d_in[8];
    const float* fcW   = (const float*)d_in[9];
    const float* fcb   = (const float*)d_in[10];

    const int N = in_sizes[0] / 128;
    const int E = in_sizes[1] / 2;
    const int C = in_sizes[10];
    const int G = out_size / C;
    float* out = (float*)d_out;

    // workspace layout
    float* A       = (float*)d_ws;                 // [N*128] features/agg
    float* B       = A + (size_t)N * 128;          // [N*128] transform out
    float* dinv    = B + (size_t)N * 128;          // [N]
    int*   counts  = (int*)(dinv + N);             // [N]
    int*   row_ptr = counts + N;                   // [N+1]
    int*   cursor  = row_ptr + N + 1;              // [N]
    int*   csr_src = cursor + N;                   // [E]
    float* pooled  = (float*)(csr_src + E);        // [G*256]

    const int* src = ei;
    const int* dst = ei + E;

    // --- CSR build (once, reused by all 3 layers) ---
    hipMemsetAsync(counts, 0, (size_t)N * sizeof(int), stream);
    hist_kernel<<<(E + 255) / 256, 256, 0, stream>>>(dst, counts, E);
    scan_kernel<<<1, 1024, 0, stream>>>(counts, row_ptr, cursor, dinv, N);
    fill_kernel<<<(E + 255) / 256, 256, 0, stream>>>(src, dst, cursor, csr_src, E);

    auto layer = [&](const float* cur, const float* W, const float* b) {
        gemm_nn<<<(N + 15) / 16, 256, 0, stream>>>(cur, W, B, N);
        agg_fused<<<(N + 7) / 8, 256, 0, stream>>>(B, row_ptr, csr_src, dinv, b, A, N);
    };
    layer(x, W1, b1);
    layer(A, W2, b2);
    layer(A, W3, b3);

    pool_kernel<<<G, 128, 0, stream>>>(A, batch, pooled, N);
    fc_kernel<<<G, 64, 0, stream>>>(pooled, fcW, fcb, out, C);
}

// Round 3
// 919.077 us; speedup vs baseline: 9.8112x; 1.2114x over previous
//
#include <hip/hip_runtime.h>
#include <hip/hip_bf16.h>

// ---------------------------------------------------------------------------
// GCN graph classification: 3x GCNConv(128->128) + mean/max pool + FC(256->10)
// Round 2: register-tiled GEMM (8x8 per thread, VALU-bound) with dinv folded
//          into the epilogue; agg becomes pure gather-add.
// ---------------------------------------------------------------------------

__global__ __launch_bounds__(256) void hist_kernel(const int* __restrict__ dst,
                                                   int* __restrict__ counts, int ne) {
    int e = blockIdx.x * 256 + threadIdx.x;
    if (e < ne) atomicAdd(&counts[dst[e]], 1);
}

// Single-block chunked exclusive scan of counts -> row_ptr/cursor; also dinv.
__global__ __launch_bounds__(1024) void scan_kernel(const int* __restrict__ counts,
                                                    int* __restrict__ row_ptr,
                                                    int* __restrict__ cursor,
                                                    float* __restrict__ dinv, int n) {
    __shared__ int wsum[16];
    int t = threadIdx.x;
    int lane = t & 63, wid = t >> 6;
    int running = 0;
    for (int base = 0; base < n; base += 1024) {
        int i = base + t;
        int v = (i < n) ? counts[i] : 0;
        int sc = v;                       // inclusive wave scan
#pragma unroll
        for (int off = 1; off < 64; off <<= 1) {
            int u = __shfl_up(sc, off, 64);
            if (lane >= off) sc += u;
        }
        if (lane == 63) wsum[wid] = sc;
        __syncthreads();
        if (wid == 0) {
            int w = (lane < 16) ? wsum[lane] : 0;
#pragma unroll
            for (int off = 1; off < 16; off <<= 1) {
                int u = __shfl_up(w, off, 64);
                if (lane >= off) w += u;
            }
            if (lane < 16) wsum[lane] = w;    // inclusive over wave sums
        }
        __syncthreads();
        int wbase = (wid == 0) ? 0 : wsum[wid - 1];
        int excl = running + wbase + (sc - v);
        if (i < n) {
            row_ptr[i] = excl;
            cursor[i]  = excl;
            dinv[i] = 1.0f / sqrtf((float)v + 1.0f);   // exact sqrt
        }
        running += wsum[15];
        __syncthreads();
    }
    if (t == 0) row_ptr[n] = running;
}

__global__ __launch_bounds__(256) void fill_kernel(const int* __restrict__ src,
                                                   const int* __restrict__ dst,
                                                   int* __restrict__ cursor,
                                                   int* __restrict__ csr_src, int ne) {
    int e = blockIdx.x * 256 + threadIdx.x;
    if (e >= ne) return;
    int pos = atomicAdd(&cursor[dst[e]], 1);
    csr_src[pos] = src[e];
}

// Y[n,128] = dinv[row] * (X[n,128] @ W[128,128]).
// 128x128 C-tile per block of 256 threads; 8x8 register tile per thread.
// K is processed in 4 phases of 32; Xs (pad 36) + Ws staged in LDS.
__global__ __launch_bounds__(256) void gemm_rt(const float* __restrict__ X,
                                               const float* __restrict__ W,
                                               const float* __restrict__ dinv,
                                               float* __restrict__ Y, int n) {
    __shared__ float Xs[128 * 36];   // 128 rows x 32 k, row pad 36 (18 KiB)
    __shared__ float Ws[32 * 128];   // 32 k x 128 cols (16 KiB)
    const int t = threadIdx.x;
    const int tr = t >> 4;           // 0..15 -> rows tr*8..tr*8+7
    const int tc = t & 15;           // 0..15 -> cols tc*8..tc*8+7
    const int rowBase = blockIdx.x * 128;

    float acc[8][8];
#pragma unroll
    for (int i = 0; i < 8; ++i)
#pragma unroll
        for (int j = 0; j < 8; ++j) acc[i][j] = 0.f;

    // staging index maps (float4 granularity)
    const int xr0 = t >> 3;          // rows t>>3 + 32j
    const int xk4 = (t & 7) * 4;     // k offset within phase
    const int wk0 = t >> 5;          // k rows t>>5 + 8j? (see loop)
    const int wc4 = (t & 31) * 4;    // col offset

    for (int ph = 0; ph < 4; ++ph) {
        if (ph) __syncthreads();     // protect LDS reuse
        // stage X: 128 rows x 32 k
#pragma unroll
        for (int j = 0; j < 4; ++j) {
            int row = xr0 + 32 * j;
            int gr = rowBase + row;
            if (gr > n - 1) gr = n - 1;           // clamp tail
            float4 v = *(const float4*)&X[(size_t)gr * 128 + ph * 32 + xk4];
            *(float4*)&Xs[row * 36 + xk4] = v;
        }
        // stage W: 32 k x 128 cols
#pragma unroll
        for (int j = 0; j < 4; ++j) {
            int kr = wk0 + 8 * j;
            float4 v = *(const float4*)&W[(size_t)(ph * 32 + kr) * 128 + wc4];
            *(float4*)&Ws[kr * 128 + wc4] = v;
        }
        __syncthreads();

#pragma unroll 4
        for (int kk = 0; kk < 32; ++kk) {
            float4 wa = *(const float4*)&Ws[kk * 128 + tc * 8];
            float4 wb = *(const float4*)&Ws[kk * 128 + tc * 8 + 4];
            float wv[8] = {wa.x, wa.y, wa.z, wa.w, wb.x, wb.y, wb.z, wb.w};
            float xv[8];
#pragma unroll
            for (int i = 0; i < 8; ++i) xv[i] = Xs[(tr * 8 + i) * 36 + kk];
#pragma unroll
            for (int i = 0; i < 8; ++i)
#pragma unroll
                for (int j = 0; j < 8; ++j)
                    acc[i][j] = fmaf(xv[i], wv[j], acc[i][j]);
        }
    }

    // epilogue: scale by dinv[row], store
#pragma unroll
    for (int i = 0; i < 8; ++i) {
        int r = rowBase + tr * 8 + i;
        if (r >= n) break;
        float dv = dinv[r];
        float4 o0 = {acc[i][0] * dv, acc[i][1] * dv, acc[i][2] * dv, acc[i][3] * dv};
        float4 o1 = {acc[i][4] * dv, acc[i][5] * dv, acc[i][6] * dv, acc[i][7] * dv};
        *(float4*)&Y[(size_t)r * 128 + tc * 8]     = o0;
        *(float4*)&Y[(size_t)r * 128 + tc * 8 + 4] = o1;
    }
}

// A[d,:] = relu( dinv[d] * ( sum_{e in row d} Y[src,:] + Y[d,:] ) + b )
// where Y is already scaled by dinv on the source side.
__global__ __launch_bounds__(256) void agg_fused(const float* __restrict__ Y,
                                                 const int* __restrict__ row_ptr,
                                                 const int* __restrict__ csr_src,
                                                 const float* __restrict__ dinv,
                                                 const float* __restrict__ b,
                                                 float* __restrict__ A, int n) {
    int node = blockIdx.x * 8 + (threadIdx.x >> 5);
    if (node >= n) return;
    int lane = threadIdx.x & 31;
    int beg = row_ptr[node], end = row_ptr[node + 1];
    float4 acc = *(const float4*)&Y[(size_t)node * 128 + lane * 4];  // self loop
    if (beg < end) {
        int s = csr_src[beg];
        for (int e = beg; e < end; ++e) {
            int snext = (e + 1 < end) ? csr_src[e + 1] : 0;  // prefetch index
            float4 v = *(const float4*)&Y[(size_t)s * 128 + lane * 4];
            acc.x += v.x; acc.y += v.y; acc.z += v.z; acc.w += v.w;
            s = snext;
        }
    }
    float dn = dinv[node];
    float4 bb = *(const float4*)&b[lane * 4];
    float4 h;
    h.x = fmaxf(fmaf(acc.x, dn, bb.x), 0.f);
    h.y = fmaxf(fmaf(acc.y, dn, bb.y), 0.f);
    h.z = fmaxf(fmaf(acc.z, dn, bb.z), 0.f);
    h.w = fmaxf(fmaf(acc.w, dn, bb.w), 0.f);
    *(float4*)&A[(size_t)node * 128 + lane * 4] = h;
}

__device__ __forceinline__ int lower_bound(const int* __restrict__ a, int n, int key) {
    int lo = 0, hi = n;
    while (lo < hi) {
        int mid = (lo + hi) >> 1;
        if (a[mid] < key) lo = mid + 1; else hi = mid;
    }
    return lo;
}

// Segmented pool over sorted batch: block per graph, thread per feature.
__global__ __launch_bounds__(128) void pool_kernel(const float* __restrict__ H,
                                                   const int* __restrict__ batch,
                                                   float* __restrict__ pooled, int n) {
    int g = blockIdx.x;
    int beg = lower_bound(batch, n, g);
    int end = lower_bound(batch, n, g + 1);
    int f = threadIdx.x;
    float s = 0.f, m = -INFINITY;
    for (int i = beg; i < end; ++i) {
        float v = H[(size_t)i * 128 + f];
        s += v;
        m = fmaxf(m, v);
    }
    float cnt = (float)(end - beg);
    pooled[(size_t)g * 256 + f]       = s / fmaxf(cnt, 1.0f);
    pooled[(size_t)g * 256 + 128 + f] = m;
}

__global__ __launch_bounds__(64) void fc_kernel(const float* __restrict__ pooled,
                                                const float* __restrict__ fcW,
                                                const float* __restrict__ fcb,
                                                float* __restrict__ out, int C) {
    int g = blockIdx.x;
    __shared__ float p[256];
    int t = threadIdx.x;
    for (int k = t; k < 256; k += 64) p[k] = pooled[(size_t)g * 256 + k];
    __syncthreads();
    if (t < C) {
        float acc = fcb[t];
        for (int k = 0; k < 256; ++k) acc = fmaf(p[k], fcW[k * C + t], acc);
        out[(size_t)g * C + t] = acc;
    }
}

extern "C" void kernel_launch(void* const* d_in, const int* in_sizes, int n_in,
                              void* d_out, int out_size, void* d_ws, size_t ws_size,
                              hipStream_t stream) {
    const float* x     = (const float*)d_in[0];
    const int*   ei    = (const int*)d_in[1];
    const int*   batch = (const int*)d_in[2];
    const float* W1    = (const float*)d_in[3];
    const float* b1    = (const float*)d_in[4];
    const float* W2    = (const float*)d_in[5];
    const float* b2    = (const float*)d_in[6];
    const float* W3    = (const float*)d_in[7];
    const float* b3    = (const float*)d_in[8];
    const float* fcW   = (const float*)d_in[9];
    const float* fcb   = (const float*)d_in[10];

    const int N = in_sizes[0] / 128;
    const int E = in_sizes[1] / 2;
    const int C = in_sizes[10];
    const int G = out_size / C;
    float* out = (float*)d_out;

    // workspace layout
    float* A       = (float*)d_ws;                 // [N*128] features/agg
    float* B       = A + (size_t)N * 128;          // [N*128] transform out
    float* dinv    = B + (size_t)N * 128;          // [N]
    int*   counts  = (int*)(dinv + N);             // [N]
    int*   row_ptr = counts + N;                   // [N+1]
    int*   cursor  = row_ptr + N + 1;              // [N]
    int*   csr_src = cursor + N;                   // [E]
    float* pooled  = (float*)(csr_src + E);        // [G*256]

    const int* src = ei;
    const int* dst = ei + E;

    // --- CSR build (once, reused by all 3 layers) ---
    hipMemsetAsync(counts, 0, (size_t)N * sizeof(int), stream);
    hist_kernel<<<(E + 255) / 256, 256, 0, stream>>>(dst, counts, E);
    scan_kernel<<<1, 1024, 0, stream>>>(counts, row_ptr, cursor, dinv, N);
    fill_kernel<<<(E + 255) / 256, 256, 0, stream>>>(src, dst, cursor, csr_src, E);

    auto layer = [&](const float* cur, const float* W, const float* b) {
        gemm_rt<<<(N + 127) / 128, 256, 0, stream>>>(cur, W, dinv, B, N);
        agg_fused<<<(N + 7) / 8, 256, 0, stream>>>(B, row_ptr, csr_src, dinv, b, A, N);
    };
    layer(x, W1, b1);
    layer(A, W2, b2);
    layer(A, W3, b3);

    pool_kernel<<<G, 128, 0, stream>>>(A, batch, pooled, N);
    fc_kernel<<<G, 64, 0, stream>>>(pooled, fcW, fcb, out, C);
}

// Round 4
// 723.197 us; speedup vs baseline: 12.4686x; 1.2709x over previous
//
#include <hip/hip_runtime.h>
#include <hip/hip_bf16.h>

// ---------------------------------------------------------------------------
// GCN graph classification: 3x GCNConv(128->128) + mean/max pool + FC(256->10)
// Round 3: 4-deep pipelined gather in agg; fill fused into GEMM1 (overlap
//          latency-bound fill with VALU-bound gemm); parallel 3-kernel scan;
//          conflict-free column-major Xs in the GEMM.
// ---------------------------------------------------------------------------

__global__ __launch_bounds__(256) void hist_kernel(const int* __restrict__ dst,
                                                   int* __restrict__ counts, int ne) {
    int e = blockIdx.x * 256 + threadIdx.x;
    if (e < ne) atomicAdd(&counts[dst[e]], 1);
}

// --- 3-phase parallel exclusive scan of counts -> row_ptr/cursor (+dinv) ---
__global__ __launch_bounds__(256) void scan_part(const int* __restrict__ counts,
                                                 int* __restrict__ partials, int n) {
    __shared__ int ws[4];
    int t = threadIdx.x;
    int base = blockIdx.x * 1024 + t * 4;
    int c0 = 0, c1 = 0, c2 = 0, c3 = 0;
    if (base + 3 < n) {
        c0 = counts[base]; c1 = counts[base + 1];
        c2 = counts[base + 2]; c3 = counts[base + 3];
    } else if (base < n) {
        c0 = counts[base];
        if (base + 1 < n) c1 = counts[base + 1];
        if (base + 2 < n) c2 = counts[base + 2];
    }
    int tsum = c0 + c1 + c2 + c3;
    int lane = t & 63, wid = t >> 6;
#pragma unroll
    for (int off = 32; off >= 1; off >>= 1) tsum += __shfl_down(tsum, off, 64);
    if (lane == 0) ws[wid] = tsum;
    __syncthreads();
    if (t == 0) partials[blockIdx.x] = ws[0] + ws[1] + ws[2] + ws[3];
}

__global__ __launch_bounds__(1024) void scan_partials(int* __restrict__ partials, int P) {
    __shared__ int wsum[16];
    int t = threadIdx.x, lane = t & 63, wid = t >> 6;
    int v = (t < P) ? partials[t] : 0;
    int sc = v;
#pragma unroll
    for (int off = 1; off < 64; off <<= 1) {
        int u = __shfl_up(sc, off, 64);
        if (lane >= off) sc += u;
    }
    if (lane == 63) wsum[wid] = sc;
    __syncthreads();
    if (wid == 0) {
        int w = (lane < 16) ? wsum[lane] : 0;
#pragma unroll
        for (int off = 1; off < 16; off <<= 1) {
            int u = __shfl_up(w, off, 64);
            if (lane >= off) w += u;
        }
        if (lane < 16) wsum[lane] = w;
    }
    __syncthreads();
    int wbase = (wid == 0) ? 0 : wsum[wid - 1];
    if (t < P) partials[t] = wbase + sc - v;   // exclusive block offsets
}

__global__ __launch_bounds__(256) void scan_apply(const int* __restrict__ counts,
                                                  const int* __restrict__ partials,
                                                  int* __restrict__ row_ptr,
                                                  int* __restrict__ cursor,
                                                  float* __restrict__ dinv,
                                                  int n, int ne) {
    __shared__ int ws[4];
    int t = threadIdx.x;
    int base = blockIdx.x * 1024 + t * 4;
    int c0 = 0, c1 = 0, c2 = 0, c3 = 0;
    if (base + 3 < n) {
        c0 = counts[base]; c1 = counts[base + 1];
        c2 = counts[base + 2]; c3 = counts[base + 3];
    } else if (base < n) {
        c0 = counts[base];
        if (base + 1 < n) c1 = counts[base + 1];
        if (base + 2 < n) c2 = counts[base + 2];
    }
    int tsum = c0 + c1 + c2 + c3;
    int lane = t & 63, wid = t >> 6;
    int sc = tsum;
#pragma unroll
    for (int off = 1; off < 64; off <<= 1) {
        int u = __shfl_up(sc, off, 64);
        if (lane >= off) sc += u;
    }
    if (lane == 63) ws[wid] = sc;
    __syncthreads();
    if (t == 0) {
        int r = 0;
#pragma unroll
        for (int i = 0; i < 4; ++i) { int x = ws[i]; ws[i] = r; r += x; }
    }
    __syncthreads();
    int excl = partials[blockIdx.x] + ws[wid] + (sc - tsum);
    if (base < n) {
        int p = excl;
        row_ptr[base] = p; cursor[base] = p;
        dinv[base] = 1.0f / sqrtf((float)c0 + 1.0f);
        if (base + 1 < n) {
            p += c0; row_ptr[base + 1] = p; cursor[base + 1] = p;
            dinv[base + 1] = 1.0f / sqrtf((float)c1 + 1.0f);
        }
        if (base + 2 < n) {
            p += c1; row_ptr[base + 2] = p; cursor[base + 2] = p;
            dinv[base + 2] = 1.0f / sqrtf((float)c2 + 1.0f);
        }
        if (base + 3 < n) {
            p += c2; row_ptr[base + 3] = p; cursor[base + 3] = p;
            dinv[base + 3] = 1.0f / sqrtf((float)c3 + 1.0f);
        }
    }
    if (blockIdx.x == 0 && t == 0) row_ptr[n] = ne;
}

// --- GEMM body: Y[row,:] = dinv[row] * (X[row,:] @ W) ----------------------
// 128x128 C-tile / 256 threads, 8x8 register tile, K in 4 phases of 32.
// Xs column-major [32 k][132 pad rows] -> conflict-free b128 reads.
__device__ __forceinline__ void gemm_body(float* __restrict__ Xs, float* __restrict__ Ws,
                                          const float* __restrict__ X,
                                          const float* __restrict__ W,
                                          const float* __restrict__ dinv,
                                          float* __restrict__ Y, int n, int blockId) {
    const int t = threadIdx.x;
    const int tr = t >> 4;           // 0..15 -> rows tr*8..tr*8+7
    const int tc = t & 15;           // 0..15 -> cols tc*8..tc*8+7
    const int rowBase = blockId * 128;

    float acc[8][8];
#pragma unroll
    for (int i = 0; i < 8; ++i)
#pragma unroll
        for (int j = 0; j < 8; ++j) acc[i][j] = 0.f;

    const int xr0 = t >> 3;          // staging: rows t>>3 + 32j
    const int xk4 = (t & 7) * 4;     // k offset within phase
    const int wk0 = t >> 5;          // staging W: k rows t>>5 + 8j
    const int wc4 = (t & 31) * 4;

    for (int ph = 0; ph < 4; ++ph) {
        if (ph) __syncthreads();
        // stage X (column-major into Xs[k][row])
#pragma unroll
        for (int j = 0; j < 4; ++j) {
            int row = xr0 + 32 * j;
            int gr = rowBase + row;
            if (gr > n - 1) gr = n - 1;
            float4 v = *(const float4*)&X[(size_t)gr * 128 + ph * 32 + xk4];
            Xs[(xk4 + 0) * 132 + row] = v.x;
            Xs[(xk4 + 1) * 132 + row] = v.y;
            Xs[(xk4 + 2) * 132 + row] = v.z;
            Xs[(xk4 + 3) * 132 + row] = v.w;
        }
        // stage W
#pragma unroll
        for (int j = 0; j < 4; ++j) {
            int kr = wk0 + 8 * j;
            float4 v = *(const float4*)&W[(size_t)(ph * 32 + kr) * 128 + wc4];
            *(float4*)&Ws[kr * 128 + wc4] = v;
        }
        __syncthreads();

#pragma unroll 4
        for (int kk = 0; kk < 32; ++kk) {
            float4 wa = *(const float4*)&Ws[kk * 128 + tc * 8];
            float4 wb = *(const float4*)&Ws[kk * 128 + tc * 8 + 4];
            float4 xa = *(const float4*)&Xs[kk * 132 + tr * 8];
            float4 xb = *(const float4*)&Xs[kk * 132 + tr * 8 + 4];
            float wv[8] = {wa.x, wa.y, wa.z, wa.w, wb.x, wb.y, wb.z, wb.w};
            float xv[8] = {xa.x, xa.y, xa.z, xa.w, xb.x, xb.y, xb.z, xb.w};
#pragma unroll
            for (int i = 0; i < 8; ++i)
#pragma unroll
                for (int j = 0; j < 8; ++j)
                    acc[i][j] = fmaf(xv[i], wv[j], acc[i][j]);
        }
    }

#pragma unroll
    for (int i = 0; i < 8; ++i) {
        int r = rowBase + tr * 8 + i;
        if (r >= n) break;
        float dv = dinv[r];
        float4 o0 = {acc[i][0] * dv, acc[i][1] * dv, acc[i][2] * dv, acc[i][3] * dv};
        float4 o1 = {acc[i][4] * dv, acc[i][5] * dv, acc[i][6] * dv, acc[i][7] * dv};
        *(float4*)&Y[(size_t)r * 128 + tc * 8]     = o0;
        *(float4*)&Y[(size_t)r * 128 + tc * 8 + 4] = o1;
    }
}

__global__ __launch_bounds__(256) void gemm_rt(const float* __restrict__ X,
                                               const float* __restrict__ W,
                                               const float* __restrict__ dinv,
                                               float* __restrict__ Y, int n) {
    __shared__ float Xs[32 * 132];
    __shared__ float Ws[32 * 128];
    gemm_body(Xs, Ws, X, W, dinv, Y, n, blockIdx.x);
}

// GEMM1 fused with CSR fill: first gemmBlocks do the GEMM tile, the rest
// grid-stride the edge list (latency-bound -> overlaps the VALU-bound GEMM).
__global__ __launch_bounds__(256) void gemm_fill(const float* __restrict__ X,
                                                 const float* __restrict__ W,
                                                 const float* __restrict__ dinv,
                                                 float* __restrict__ Y, int n,
                                                 const int* __restrict__ src,
                                                 const int* __restrict__ dst,
                                                 int* __restrict__ cursor,
                                                 int* __restrict__ csr_src, int ne,
                                                 int gemmBlocks, int fillBlocks) {
    __shared__ float Xs[32 * 132];
    __shared__ float Ws[32 * 128];
    if ((int)blockIdx.x < gemmBlocks) {
        gemm_body(Xs, Ws, X, W, dinv, Y, n, blockIdx.x);
        return;
    }
    int fb = blockIdx.x - gemmBlocks;
    int stride = fillBlocks * 256;
    for (int e0 = fb * 256 + (int)threadIdx.x; e0 < ne; e0 += 4 * stride) {
#pragma unroll
        for (int u = 0; u < 4; ++u) {
            int e = e0 + u * stride;
            if (e < ne) {
                int d = dst[e], s = src[e];
                int pos = atomicAdd(&cursor[d], 1);
                csr_src[pos] = s;
            }
        }
    }
}

// A[d,:] = relu( dinv[d] * ( sum_{e in row d} Y[src,:] + Y[d,:] ) + b )
// 4-deep pipelined gather: 4 independent index + value loads in flight.
__global__ __launch_bounds__(256) void agg_fused(const float* __restrict__ Y,
                                                 const int* __restrict__ row_ptr,
                                                 const int* __restrict__ csr_src,
                                                 const float* __restrict__ dinv,
                                                 const float* __restrict__ b,
                                                 float* __restrict__ A, int n) {
    int node = blockIdx.x * 8 + (threadIdx.x >> 5);
    if (node >= n) return;
    int lane = threadIdx.x & 31;
    int lo = lane * 4;
    int beg = row_ptr[node], end = row_ptr[node + 1];
    float4 acc = *(const float4*)&Y[(size_t)node * 128 + lo];   // self loop
    int e = beg;
    for (; e + 4 <= end; e += 4) {
        int s0 = csr_src[e + 0];
        int s1 = csr_src[e + 1];
        int s2 = csr_src[e + 2];
        int s3 = csr_src[e + 3];
        float4 v0 = *(const float4*)&Y[(size_t)s0 * 128 + lo];
        float4 v1 = *(const float4*)&Y[(size_t)s1 * 128 + lo];
        float4 v2 = *(const float4*)&Y[(size_t)s2 * 128 + lo];
        float4 v3 = *(const float4*)&Y[(size_t)s3 * 128 + lo];
        acc.x += (v0.x + v1.x) + (v2.x + v3.x);
        acc.y += (v0.y + v1.y) + (v2.y + v3.y);
        acc.z += (v0.z + v1.z) + (v2.z + v3.z);
        acc.w += (v0.w + v1.w) + (v2.w + v3.w);
    }
    for (; e < end; ++e) {
        int s = csr_src[e];
        float4 v = *(const float4*)&Y[(size_t)s * 128 + lo];
        acc.x += v.x; acc.y += v.y; acc.z += v.z; acc.w += v.w;
    }
    float dn = dinv[node];
    float4 bb = *(const float4*)&b[lo];
    float4 h;
    h.x = fmaxf(fmaf(acc.x, dn, bb.x), 0.f);
    h.y = fmaxf(fmaf(acc.y, dn, bb.y), 0.f);
    h.z = fmaxf(fmaf(acc.z, dn, bb.z), 0.f);
    h.w = fmaxf(fmaf(acc.w, dn, bb.w), 0.f);
    *(float4*)&A[(size_t)node * 128 + lo] = h;
}

__device__ __forceinline__ int lower_bound(const int* __restrict__ a, int n, int key) {
    int lo = 0, hi = n;
    while (lo < hi) {
        int mid = (lo + hi) >> 1;
        if (a[mid] < key) lo = mid + 1; else hi = mid;
    }
    return lo;
}

__global__ __launch_bounds__(128) void pool_kernel(const float* __restrict__ H,
                                                   const int* __restrict__ batch,
                                                   float* __restrict__ pooled, int n) {
    int g = blockIdx.x;
    int beg = lower_bound(batch, n, g);
    int end = lower_bound(batch, n, g + 1);
    int f = threadIdx.x;
    float s = 0.f, m = -INFINITY;
    for (int i = beg; i < end; ++i) {
        float v = H[(size_t)i * 128 + f];
        s += v;
        m = fmaxf(m, v);
    }
    float cnt = (float)(end - beg);
    pooled[(size_t)g * 256 + f]       = s / fmaxf(cnt, 1.0f);
    pooled[(size_t)g * 256 + 128 + f] = m;
}

__global__ __launch_bounds__(64) void fc_kernel(const float* __restrict__ pooled,
                                                const float* __restrict__ fcW,
                                                const float* __restrict__ fcb,
                                                float* __restrict__ out, int C) {
    int g = blockIdx.x;
    __shared__ float p[256];
    int t = threadIdx.x;
    for (int k = t; k < 256; k += 64) p[k] = pooled[(size_t)g * 256 + k];
    __syncthreads();
    if (t < C) {
        float acc = fcb[t];
        for (int k = 0; k < 256; ++k) acc = fmaf(p[k], fcW[k * C + t], acc);
        out[(size_t)g * C + t] = acc;
    }
}

extern "C" void kernel_launch(void* const* d_in, const int* in_sizes, int n_in,
                              void* d_out, int out_size, void* d_ws, size_t ws_size,
                              hipStream_t stream) {
    const float* x     = (const float*)d_in[0];
    const int*   ei    = (const int*)d_in[1];
    const int*   batch = (const int*)d_in[2];
    const float* W1    = (const float*)d_in[3];
    const float* b1    = (const float*)d_in[4];
    const float* W2    = (const float*)d_in[5];
    const float* b2    = (const float*)d_in[6];
    const float* W3    = (const float*)d_in[7];
    const float* b3    = (const float*)d_in[8];
    const float* fcW   = (const float*)d_in[9];
    const float* fcb   = (const float*)d_in[10];

    const int N = in_sizes[0] / 128;
    const int E = in_sizes[1] / 2;
    const int C = in_sizes[10];
    const int G = out_size / C;
    float* out = (float*)d_out;

    // workspace layout
    float* A        = (float*)d_ws;                 // [N*128]
    float* B        = A + (size_t)N * 128;          // [N*128]
    float* dinv     = B + (size_t)N * 128;          // [N]
    int*   counts   = (int*)(dinv + N);             // [N]
    int*   partials = counts + N;                   // [1024]
    int*   row_ptr  = partials + 1024;              // [N+4]
    int*   cursor   = row_ptr + N + 4;              // [N]
    int*   csr_src  = cursor + N;                   // [E]
    float* pooled   = (float*)(csr_src + E);        // [G*256]

    const int* src = ei;
    const int* dst = ei + E;

    const int scanBlocks = (N + 1023) / 1024;
    const int gemmBlocks = (N + 127) / 128;
    const int fillBlocks = 1024;

    // --- CSR build (counts -> scan -> [fill fused with gemm1]) ---
    hipMemsetAsync(counts, 0, (size_t)N * sizeof(int), stream);
    hist_kernel<<<(E + 255) / 256, 256, 0, stream>>>(dst, counts, E);
    scan_part<<<scanBlocks, 256, 0, stream>>>(counts, partials, N);
    scan_partials<<<1, 1024, 0, stream>>>(partials, scanBlocks);
    scan_apply<<<scanBlocks, 256, 0, stream>>>(counts, partials, row_ptr, cursor, dinv, N, E);

    // layer 1: gemm fused with CSR fill (independent work, different pipes)
    gemm_fill<<<gemmBlocks + fillBlocks, 256, 0, stream>>>(
        x, W1, dinv, B, N, src, dst, cursor, csr_src, E, gemmBlocks, fillBlocks);
    agg_fused<<<(N + 7) / 8, 256, 0, stream>>>(B, row_ptr, csr_src, dinv, b1, A, N);

    // layers 2, 3
    gemm_rt<<<gemmBlocks, 256, 0, stream>>>(A, W2, dinv, B, N);
    agg_fused<<<(N + 7) / 8, 256, 0, stream>>>(B, row_ptr, csr_src, dinv, b2, A, N);
    gemm_rt<<<gemmBlocks, 256, 0, stream>>>(A, W3, dinv, B, N);
    agg_fused<<<(N + 7) / 8, 256, 0, stream>>>(B, row_ptr, csr_src, dinv, b3, A, N);

    pool_kernel<<<G, 128, 0, stream>>>(A, batch, pooled, N);
    fc_kernel<<<G, 64, 0, stream>>>(pooled, fcW, fcb, out, C);
}

// Round 5
// 545.599 us; speedup vs baseline: 16.5272x; 1.3255x over previous
//
#include <hip/hip_runtime.h>
#include <hip/hip_fp16.h>

// ---------------------------------------------------------------------------
// GCN graph classification: 3x GCNConv(128->128) + mean/max pool + FC(256->10)
// Round 4: fp16 storage for internal feature maps (Y, A) halves the gather
//          traffic in agg and the GEMM stream traffic; fp32 accumulation
//          everywhere. Structure otherwise as round 3.
// ---------------------------------------------------------------------------

__device__ __forceinline__ void addHalf8(float* a, uint4 v) {
    const __half2* h = reinterpret_cast<const __half2*>(&v);
#pragma unroll
    for (int j = 0; j < 4; ++j) {
        float2 f = __half22float2(h[j]);
        a[2 * j]     += f.x;
        a[2 * j + 1] += f.y;
    }
}

__device__ __forceinline__ uint4 packHalf8(const float* a) {
    union { __half2 h[4]; uint4 u; } r;
#pragma unroll
    for (int j = 0; j < 4; ++j) r.h[j] = __floats2half2_rn(a[2 * j], a[2 * j + 1]);
    return r.u;
}

__global__ __launch_bounds__(256) void hist_kernel(const int* __restrict__ dst,
                                                   int* __restrict__ counts, int ne) {
    int e = blockIdx.x * 256 + threadIdx.x;
    if (e < ne) atomicAdd(&counts[dst[e]], 1);
}

// --- 3-phase parallel exclusive scan of counts -> row_ptr/cursor (+dinv) ---
__global__ __launch_bounds__(256) void scan_part(const int* __restrict__ counts,
                                                 int* __restrict__ partials, int n) {
    __shared__ int ws[4];
    int t = threadIdx.x;
    int base = blockIdx.x * 1024 + t * 4;
    int c0 = 0, c1 = 0, c2 = 0, c3 = 0;
    if (base + 3 < n) {
        c0 = counts[base]; c1 = counts[base + 1];
        c2 = counts[base + 2]; c3 = counts[base + 3];
    } else if (base < n) {
        c0 = counts[base];
        if (base + 1 < n) c1 = counts[base + 1];
        if (base + 2 < n) c2 = counts[base + 2];
    }
    int tsum = c0 + c1 + c2 + c3;
    int lane = t & 63, wid = t >> 6;
#pragma unroll
    for (int off = 32; off >= 1; off >>= 1) tsum += __shfl_down(tsum, off, 64);
    if (lane == 0) ws[wid] = tsum;
    __syncthreads();
    if (t == 0) partials[blockIdx.x] = ws[0] + ws[1] + ws[2] + ws[3];
}

__global__ __launch_bounds__(1024) void scan_partials(int* __restrict__ partials, int P) {
    __shared__ int wsum[16];
    int t = threadIdx.x, lane = t & 63, wid = t >> 6;
    int v = (t < P) ? partials[t] : 0;
    int sc = v;
#pragma unroll
    for (int off = 1; off < 64; off <<= 1) {
        int u = __shfl_up(sc, off, 64);
        if (lane >= off) sc += u;
    }
    if (lane == 63) wsum[wid] = sc;
    __syncthreads();
    if (wid == 0) {
        int w = (lane < 16) ? wsum[lane] : 0;
#pragma unroll
        for (int off = 1; off < 16; off <<= 1) {
            int u = __shfl_up(w, off, 64);
            if (lane >= off) w += u;
        }
        if (lane < 16) wsum[lane] = w;
    }
    __syncthreads();
    int wbase = (wid == 0) ? 0 : wsum[wid - 1];
    if (t < P) partials[t] = wbase + sc - v;   // exclusive block offsets
}

__global__ __launch_bounds__(256) void scan_apply(const int* __restrict__ counts,
                                                  const int* __restrict__ partials,
                                                  int* __restrict__ row_ptr,
                                                  int* __restrict__ cursor,
                                                  float* __restrict__ dinv,
                                                  int n, int ne) {
    __shared__ int ws[4];
    int t = threadIdx.x;
    int base = blockIdx.x * 1024 + t * 4;
    int c0 = 0, c1 = 0, c2 = 0, c3 = 0;
    if (base + 3 < n) {
        c0 = counts[base]; c1 = counts[base + 1];
        c2 = counts[base + 2]; c3 = counts[base + 3];
    } else if (base < n) {
        c0 = counts[base];
        if (base + 1 < n) c1 = counts[base + 1];
        if (base + 2 < n) c2 = counts[base + 2];
    }
    int tsum = c0 + c1 + c2 + c3;
    int lane = t & 63, wid = t >> 6;
    int sc = tsum;
#pragma unroll
    for (int off = 1; off < 64; off <<= 1) {
        int u = __shfl_up(sc, off, 64);
        if (lane >= off) sc += u;
    }
    if (lane == 63) ws[wid] = sc;
    __syncthreads();
    if (t == 0) {
        int r = 0;
#pragma unroll
        for (int i = 0; i < 4; ++i) { int x = ws[i]; ws[i] = r; r += x; }
    }
    __syncthreads();
    int excl = partials[blockIdx.x] + ws[wid] + (sc - tsum);
    if (base < n) {
        int p = excl;
        row_ptr[base] = p; cursor[base] = p;
        dinv[base] = 1.0f / sqrtf((float)c0 + 1.0f);
        if (base + 1 < n) {
            p += c0; row_ptr[base + 1] = p; cursor[base + 1] = p;
            dinv[base + 1] = 1.0f / sqrtf((float)c1 + 1.0f);
        }
        if (base + 2 < n) {
            p += c1; row_ptr[base + 2] = p; cursor[base + 2] = p;
            dinv[base + 2] = 1.0f / sqrtf((float)c2 + 1.0f);
        }
        if (base + 3 < n) {
            p += c2; row_ptr[base + 3] = p; cursor[base + 3] = p;
            dinv[base + 3] = 1.0f / sqrtf((float)c3 + 1.0f);
        }
    }
    if (blockIdx.x == 0 && t == 0) row_ptr[n] = ne;
}

// --- GEMM body: Y[row,:] = fp16( dinv[row] * (X[row,:] @ W) ) --------------
// 128x128 C-tile / 256 threads, 8x8 register tile, K in 4 phases of 32.
// Xs fp32 column-major [32 k][132 rows] -> conflict-free b128 reads; fp16
// input is converted during staging (2-way LDS write conflicts = free).
template <bool HALF_IN>
__device__ __forceinline__ void gemm_body(float* __restrict__ Xs, float* __restrict__ Ws,
                                          const void* __restrict__ Xv,
                                          const float* __restrict__ W,
                                          const float* __restrict__ dinv,
                                          __half* __restrict__ Y, int n, int blockId) {
    const int t = threadIdx.x;
    const int tr = t >> 4;           // 0..15 -> rows tr*8..tr*8+7
    const int tc = t & 15;           // 0..15 -> cols tc*8..tc*8+7
    const int rowBase = blockId * 128;

    float acc[8][8];
#pragma unroll
    for (int i = 0; i < 8; ++i)
#pragma unroll
        for (int j = 0; j < 8; ++j) acc[i][j] = 0.f;

    for (int ph = 0; ph < 4; ++ph) {
        if (ph) __syncthreads();
        if constexpr (!HALF_IN) {
            const float* X = (const float*)Xv;
            const int xr0 = t >> 3;
            const int xk4 = (t & 7) * 4;
#pragma unroll
            for (int j = 0; j < 4; ++j) {
                int row = xr0 + 32 * j;
                int gr = rowBase + row;
                if (gr > n - 1) gr = n - 1;
                float4 v = *(const float4*)&X[(size_t)gr * 128 + ph * 32 + xk4];
                Xs[(xk4 + 0) * 132 + row] = v.x;
                Xs[(xk4 + 1) * 132 + row] = v.y;
                Xs[(xk4 + 2) * 132 + row] = v.z;
                Xs[(xk4 + 3) * 132 + row] = v.w;
            }
        } else {
            const __half* X = (const __half*)Xv;
            const int row = t >> 1;
            const int q = t & 1;
            int gr = rowBase + row;
            if (gr > n - 1) gr = n - 1;
#pragma unroll
            for (int rep = 0; rep < 2; ++rep) {
                int o = q * 8 + rep * 16;
                uint4 v = *(const uint4*)&X[(size_t)gr * 128 + ph * 32 + o];
                const __half2* h2 = (const __half2*)&v;
#pragma unroll
                for (int j = 0; j < 4; ++j) {
                    float2 f = __half22float2(h2[j]);
                    Xs[(o + 2 * j + 0) * 132 + row] = f.x;
                    Xs[(o + 2 * j + 1) * 132 + row] = f.y;
                }
            }
        }
        // stage W
        const int wk0 = t >> 5;
        const int wc4 = (t & 31) * 4;
#pragma unroll
        for (int j = 0; j < 4; ++j) {
            int kr = wk0 + 8 * j;
            float4 v = *(const float4*)&W[(size_t)(ph * 32 + kr) * 128 + wc4];
            *(float4*)&Ws[kr * 128 + wc4] = v;
        }
        __syncthreads();

#pragma unroll 4
        for (int kk = 0; kk < 32; ++kk) {
            float4 wa = *(const float4*)&Ws[kk * 128 + tc * 8];
            float4 wb = *(const float4*)&Ws[kk * 128 + tc * 8 + 4];
            float4 xa = *(const float4*)&Xs[kk * 132 + tr * 8];
            float4 xb = *(const float4*)&Xs[kk * 132 + tr * 8 + 4];
            float wv[8] = {wa.x, wa.y, wa.z, wa.w, wb.x, wb.y, wb.z, wb.w};
            float xv[8] = {xa.x, xa.y, xa.z, xa.w, xb.x, xb.y, xb.z, xb.w};
#pragma unroll
            for (int i = 0; i < 8; ++i)
#pragma unroll
                for (int j = 0; j < 8; ++j)
                    acc[i][j] = fmaf(xv[i], wv[j], acc[i][j]);
        }
    }

#pragma unroll
    for (int i = 0; i < 8; ++i) {
        int r = rowBase + tr * 8 + i;
        if (r >= n) break;
        float dv = dinv[r];
        float o[8];
#pragma unroll
        for (int j = 0; j < 8; ++j) o[j] = acc[i][j] * dv;
        *(uint4*)&Y[(size_t)r * 128 + tc * 8] = packHalf8(o);
    }
}

__global__ __launch_bounds__(256) void gemm_h(const __half* __restrict__ X,
                                              const float* __restrict__ W,
                                              const float* __restrict__ dinv,
                                              __half* __restrict__ Y, int n) {
    __shared__ float Xs[32 * 132];
    __shared__ float Ws[32 * 128];
    gemm_body<true>(Xs, Ws, X, W, dinv, Y, n, blockIdx.x);
}

// GEMM1 (fp32 input) fused with CSR fill in the surplus blocks.
__global__ __launch_bounds__(256) void gemm_fill(const float* __restrict__ X,
                                                 const float* __restrict__ W,
                                                 const float* __restrict__ dinv,
                                                 __half* __restrict__ Y, int n,
                                                 const int* __restrict__ src,
                                                 const int* __restrict__ dst,
                                                 int* __restrict__ cursor,
                                                 int* __restrict__ csr_src, int ne,
                                                 int gemmBlocks, int fillBlocks) {
    __shared__ float Xs[32 * 132];
    __shared__ float Ws[32 * 128];
    if ((int)blockIdx.x < gemmBlocks) {
        gemm_body<false>(Xs, Ws, X, W, dinv, Y, n, blockIdx.x);
        return;
    }
    int fb = blockIdx.x - gemmBlocks;
    int stride = fillBlocks * 256;
    for (int e0 = fb * 256 + (int)threadIdx.x; e0 < ne; e0 += 4 * stride) {
#pragma unroll
        for (int u = 0; u < 4; ++u) {
            int e = e0 + u * stride;
            if (e < ne) {
                int d = dst[e], s = src[e];
                int pos = atomicAdd(&cursor[d], 1);
                csr_src[pos] = s;
            }
        }
    }
}

// A[d,:] = fp16( relu( dinv[d]*(sum_{e in row d} Y[src,:] + Y[d,:]) + b ) )
// 16 lanes/node, 8 halves (16 B) per lane, fp32 accumulation, 4-deep gather.
__global__ __launch_bounds__(256) void agg_fused(const __half* __restrict__ Y,
                                                 const int* __restrict__ row_ptr,
                                                 const int* __restrict__ csr_src,
                                                 const float* __restrict__ dinv,
                                                 const float* __restrict__ b,
                                                 __half* __restrict__ A, int n) {
    int node = blockIdx.x * 16 + (threadIdx.x >> 4);
    if (node >= n) return;
    int lane = threadIdx.x & 15;
    int lo = lane * 8;
    int beg = row_ptr[node], end = row_ptr[node + 1];
    float acc[8] = {0.f, 0.f, 0.f, 0.f, 0.f, 0.f, 0.f, 0.f};
    addHalf8(acc, *(const uint4*)&Y[(size_t)node * 128 + lo]);   // self loop
    int e = beg;
    for (; e + 4 <= end; e += 4) {
        int s0 = csr_src[e + 0];
        int s1 = csr_src[e + 1];
        int s2 = csr_src[e + 2];
        int s3 = csr_src[e + 3];
        uint4 v0 = *(const uint4*)&Y[(size_t)s0 * 128 + lo];
        uint4 v1 = *(const uint4*)&Y[(size_t)s1 * 128 + lo];
        uint4 v2 = *(const uint4*)&Y[(size_t)s2 * 128 + lo];
        uint4 v3 = *(const uint4*)&Y[(size_t)s3 * 128 + lo];
        addHalf8(acc, v0); addHalf8(acc, v1);
        addHalf8(acc, v2); addHalf8(acc, v3);
    }
    for (; e < end; ++e) {
        int s = csr_src[e];
        addHalf8(acc, *(const uint4*)&Y[(size_t)s * 128 + lo]);
    }
    float dn = dinv[node];
    float h[8];
#pragma unroll
    for (int j = 0; j < 8; ++j) h[j] = fmaxf(fmaf(acc[j], dn, b[lo + j]), 0.f);
    *(uint4*)&A[(size_t)node * 128 + lo] = packHalf8(h);
}

__device__ __forceinline__ int lower_bound(const int* __restrict__ a, int n, int key) {
    int lo = 0, hi = n;
    while (lo < hi) {
        int mid = (lo + hi) >> 1;
        if (a[mid] < key) lo = mid + 1; else hi = mid;
    }
    return lo;
}

__global__ __launch_bounds__(128) void pool_kernel(const __half* __restrict__ H,
                                                   const int* __restrict__ batch,
                                                   float* __restrict__ pooled, int n) {
    int g = blockIdx.x;
    int beg = lower_bound(batch, n, g);
    int end = lower_bound(batch, n, g + 1);
    int f = threadIdx.x;
    float s = 0.f, m = -INFINITY;
    for (int i = beg; i < end; ++i) {
        float v = __half2float(H[(size_t)i * 128 + f]);
        s += v;
        m = fmaxf(m, v);
    }
    float cnt = (float)(end - beg);
    pooled[(size_t)g * 256 + f]       = s / fmaxf(cnt, 1.0f);
    pooled[(size_t)g * 256 + 128 + f] = m;
}

__global__ __launch_bounds__(64) void fc_kernel(const float* __restrict__ pooled,
                                                const float* __restrict__ fcW,
                                                const float* __restrict__ fcb,
                                                float* __restrict__ out, int C) {
    int g = blockIdx.x;
    __shared__ float p[256];
    int t = threadIdx.x;
    for (int k = t; k < 256; k += 64) p[k] = pooled[(size_t)g * 256 + k];
    __syncthreads();
    if (t < C) {
        float acc = fcb[t];
        for (int k = 0; k < 256; ++k) acc = fmaf(p[k], fcW[k * C + t], acc);
        out[(size_t)g * C + t] = acc;
    }
}

extern "C" void kernel_launch(void* const* d_in, const int* in_sizes, int n_in,
                              void* d_out, int out_size, void* d_ws, size_t ws_size,
                              hipStream_t stream) {
    const float* x     = (const float*)d_in[0];
    const int*   ei    = (const int*)d_in[1];
    const int*   batch = (const int*)d_in[2];
    const float* W1    = (const float*)d_in[3];
    const float* b1    = (const float*)d_in[4];
    const float* W2    = (const float*)d_in[5];
    const float* b2    = (const float*)d_in[6];
    const float* W3    = (const float*)d_in[7];
    const float* b3    = (const float*)d_in[8];
    const float* fcW   = (const float*)d_in[9];
    const float* fcb   = (const float*)d_in[10];

    const int N = in_sizes[0] / 128;
    const int E = in_sizes[1] / 2;
    const int C = in_sizes[10];
    const int G = out_size / C;
    float* out = (float*)d_out;

    // workspace layout (fp16 feature maps first: 16B-aligned at base)
    __half* Yh      = (__half*)d_ws;                // [N*128]
    __half* Ah      = Yh + (size_t)N * 128;         // [N*128]
    float* dinv     = (float*)(Ah + (size_t)N * 128); // [N]
    float* pooled   = dinv + N;                     // [G*256]
    int*   counts   = (int*)(pooled + (size_t)G * 256); // [N]
    int*   partials = counts + N;                   // [1024]
    int*   row_ptr  = partials + 1024;              // [N+4]
    int*   cursor   = row_ptr + N + 4;              // [N]
    int*   csr_src  = cursor + N;                   // [E]

    const int* src = ei;
    const int* dst = ei + E;

    const int scanBlocks = (N + 1023) / 1024;
    const int gemmBlocks = (N + 127) / 128;
    const int fillBlocks = 1024;

    // --- CSR build (counts -> scan -> [fill fused with gemm1]) ---
    hipMemsetAsync(counts, 0, (size_t)N * sizeof(int), stream);
    hist_kernel<<<(E + 255) / 256, 256, 0, stream>>>(dst, counts, E);
    scan_part<<<scanBlocks, 256, 0, stream>>>(counts, partials, N);
    scan_partials<<<1, 1024, 0, stream>>>(partials, scanBlocks);
    scan_apply<<<scanBlocks, 256, 0, stream>>>(counts, partials, row_ptr, cursor, dinv, N, E);

    // layer 1: gemm (fp32 in, fp16 out) fused with CSR fill
    gemm_fill<<<gemmBlocks + fillBlocks, 256, 0, stream>>>(
        x, W1, dinv, Yh, N, src, dst, cursor, csr_src, E, gemmBlocks, fillBlocks);
    agg_fused<<<(N + 15) / 16, 256, 0, stream>>>(Yh, row_ptr, csr_src, dinv, b1, Ah, N);

    // layers 2, 3 (fp16 in, fp16 out)
    gemm_h<<<gemmBlocks, 256, 0, stream>>>(Ah, W2, dinv, Yh, N);
    agg_fused<<<(N + 15) / 16, 256, 0, stream>>>(Yh, row_ptr, csr_src, dinv, b2, Ah, N);
    gemm_h<<<gemmBlocks, 256, 0, stream>>>(Ah, W3, dinv, Yh, N);
    agg_fused<<<(N + 15) / 16, 256, 0, stream>>>(Yh, row_ptr, csr_src, dinv, b3, Ah, N);

    pool_kernel<<<G, 128, 0, stream>>>(Ah, batch, pooled, N);
    fc_kernel<<<G, 64, 0, stream>>>(pooled, fcW, fcb, out, C);
}

// Round 6
// 472.920 us; speedup vs baseline: 19.0672x; 1.1537x over previous
//
#include <hip/hip_runtime.h>
#include <hip/hip_fp16.h>

// ---------------------------------------------------------------------------
// GCN graph classification: 3x GCNConv(128->128) + mean/max pool + FC(256->10)
// Round 6: MFMA (16x16x32 f16) GEMMs with W pre-packed into fragment order
//          (swapped operands: A=W-frag, B=X-frag -> packed 8B stores);
//          XCD-sliced hist/fill (dst-space partitioned by block residue) to
//          kill scattered-write amplification and cross-XCD atomic thrash.
// ---------------------------------------------------------------------------

typedef _Float16 f16;
typedef f16 f16x8 __attribute__((ext_vector_type(8)));
typedef f16 f16x4 __attribute__((ext_vector_type(4)));
typedef float f32x4 __attribute__((ext_vector_type(4)));

// --- prep: pack W1/W2/W3 into MFMA A-fragment order (fp16) + sliced hist ---
// wf slot (ch,ct,t,lane): 8 halves j -> W[k = t*32+(lane>>4)*8+j][c = ch*64+ct*16+(lane&15)]
__global__ __launch_bounds__(256) void prep_kernel(const float* __restrict__ W1,
                                                   const float* __restrict__ W2,
                                                   const float* __restrict__ W3,
                                                   f16x8* __restrict__ wf,
                                                   const int* __restrict__ dst,
                                                   int* __restrict__ counts, int ne) {
    int bid = blockIdx.x;
    if (bid < 24) {
        int layer = bid >> 3;
        const float* W = (layer == 0) ? W1 : (layer == 1 ? W2 : W3);
        int tid2 = (bid & 7) * 256 + (int)threadIdx.x;   // 0..2047
        int ch = tid2 >> 10;
        int ct = (tid2 >> 8) & 3;
        int t  = (tid2 >> 6) & 3;
        int l  = tid2 & 63;
        int c  = ch * 64 + ct * 16 + (l & 15);
        int k0 = t * 32 + ((l >> 4) << 3);
        f16x8 v;
#pragma unroll
        for (int j = 0; j < 8; ++j) v[j] = (f16)W[(size_t)(k0 + j) * 128 + c];
        wf[layer * 2048 + tid2] = v;
        return;
    }
    // sliced histogram: slice s handles dst with ((d>>14)&7)==s; the 128
    // blocks of a slice stream the full edge list (coalesced), atomics stay
    // in one XCD's L2.
    int fb = bid - 24;
    int slice = fb & 7;
    const int stride = 128 * 256;
    for (int e = (fb >> 3) * 256 + (int)threadIdx.x; e < ne; e += stride) {
        int d = dst[e];
        if (((d >> 14) & 7) == slice) atomicAdd(&counts[d], 1);
    }
}

// --- 3-phase parallel exclusive scan of counts -> row_ptr/cursor (+dinv) ---
__global__ __launch_bounds__(256) void scan_part(const int* __restrict__ counts,
                                                 int* __restrict__ partials, int n) {
    __shared__ int ws[4];
    int t = threadIdx.x;
    int base = blockIdx.x * 1024 + t * 4;
    int c0 = 0, c1 = 0, c2 = 0, c3 = 0;
    if (base + 3 < n) {
        c0 = counts[base]; c1 = counts[base + 1];
        c2 = counts[base + 2]; c3 = counts[base + 3];
    } else if (base < n) {
        c0 = counts[base];
        if (base + 1 < n) c1 = counts[base + 1];
        if (base + 2 < n) c2 = counts[base + 2];
    }
    int tsum = c0 + c1 + c2 + c3;
    int lane = t & 63, wid = t >> 6;
#pragma unroll
    for (int off = 32; off >= 1; off >>= 1) tsum += __shfl_down(tsum, off, 64);
    if (lane == 0) ws[wid] = tsum;
    __syncthreads();
    if (t == 0) partials[blockIdx.x] = ws[0] + ws[1] + ws[2] + ws[3];
}

__global__ __launch_bounds__(1024) void scan_partials(int* __restrict__ partials, int P) {
    __shared__ int wsum[16];
    int t = threadIdx.x, lane = t & 63, wid = t >> 6;
    int v = (t < P) ? partials[t] : 0;
    int sc = v;
#pragma unroll
    for (int off = 1; off < 64; off <<= 1) {
        int u = __shfl_up(sc, off, 64);
        if (lane >= off) sc += u;
    }
    if (lane == 63) wsum[wid] = sc;
    __syncthreads();
    if (wid == 0) {
        int w = (lane < 16) ? wsum[lane] : 0;
#pragma unroll
        for (int off = 1; off < 16; off <<= 1) {
            int u = __shfl_up(w, off, 64);
            if (lane >= off) w += u;
        }
        if (lane < 16) wsum[lane] = w;
    }
    __syncthreads();
    int wbase = (wid == 0) ? 0 : wsum[wid - 1];
    if (t < P) partials[t] = wbase + sc - v;   // exclusive block offsets
}

__global__ __launch_bounds__(256) void scan_apply(const int* __restrict__ counts,
                                                  const int* __restrict__ partials,
                                                  int* __restrict__ row_ptr,
                                                  int* __restrict__ cursor,
                                                  float* __restrict__ dinv,
                                                  int n, int ne) {
    __shared__ int ws[4];
    int t = threadIdx.x;
    int base = blockIdx.x * 1024 + t * 4;
    int c0 = 0, c1 = 0, c2 = 0, c3 = 0;
    if (base + 3 < n) {
        c0 = counts[base]; c1 = counts[base + 1];
        c2 = counts[base + 2]; c3 = counts[base + 3];
    } else if (base < n) {
        c0 = counts[base];
        if (base + 1 < n) c1 = counts[base + 1];
        if (base + 2 < n) c2 = counts[base + 2];
    }
    int tsum = c0 + c1 + c2 + c3;
    int lane = t & 63, wid = t >> 6;
    int sc = tsum;
#pragma unroll
    for (int off = 1; off < 64; off <<= 1) {
        int u = __shfl_up(sc, off, 64);
        if (lane >= off) sc += u;
    }
    if (lane == 63) ws[wid] = sc;
    __syncthreads();
    if (t == 0) {
        int r = 0;
#pragma unroll
        for (int i = 0; i < 4; ++i) { int x = ws[i]; ws[i] = r; r += x; }
    }
    __syncthreads();
    int excl = partials[blockIdx.x] + ws[wid] + (sc - tsum);
    if (base < n) {
        int p = excl;
        row_ptr[base] = p; cursor[base] = p;
        dinv[base] = 1.0f / sqrtf((float)c0 + 1.0f);
        if (base + 1 < n) {
            p += c0; row_ptr[base + 1] = p; cursor[base + 1] = p;
            dinv[base + 1] = 1.0f / sqrtf((float)c1 + 1.0f);
        }
        if (base + 2 < n) {
            p += c1; row_ptr[base + 2] = p; cursor[base + 2] = p;
            dinv[base + 2] = 1.0f / sqrtf((float)c2 + 1.0f);
        }
        if (base + 3 < n) {
            p += c2; row_ptr[base + 3] = p; cursor[base + 3] = p;
            dinv[base + 3] = 1.0f / sqrtf((float)c3 + 1.0f);
        }
    }
    if (blockIdx.x == 0 && t == 0) row_ptr[n] = ne;
}

// --- MFMA GEMM core: Y[m,:] = fp16( dinv[m] * (X[m,:] @ W) ) ---------------
// Block = 256 thr = 4 waves; wave (w>>1) -> 32-row group, (w&1) -> 64-col half.
// Swapped operands: A-frag = W (M-axis = out cols), B-frag = X (N-axis = rows).
// D mapping (16x16x32): D[row=c=(l>>4)*4+reg][col=m=l&15]
//   -> lane stores 4 consecutive cols of one row: packed 8B store.
template <bool XHALF>
__device__ __forceinline__ void gemm_core(const void* __restrict__ Xv,
                                          const f16x8* __restrict__ wf,
                                          const float* __restrict__ dinv,
                                          f16* __restrict__ Y, int n, int bid) {
    const int tid = threadIdx.x;
    const int l = tid & 63;
    const int w = tid >> 6;
    const int ch = w & 1;                       // column half (0/1) -> 64 cols
    const int row0 = bid * 64 + (w >> 1) * 32;  // 32-row group
    const int m = l & 15;
    const int kg = l >> 4;

    // preload 16 W fragments (L2-hot, coalesced 16B/lane)
    f16x8 bw[4][4];
#pragma unroll
    for (int ct = 0; ct < 4; ++ct)
#pragma unroll
        for (int t = 0; t < 4; ++t)
            bw[ct][t] = wf[((ch * 4 + ct) * 4 + t) * 64 + l];

    f32x4 acc[2][4];
#pragma unroll
    for (int mt = 0; mt < 2; ++mt)
#pragma unroll
        for (int ct = 0; ct < 4; ++ct) acc[mt][ct] = (f32x4){0.f, 0.f, 0.f, 0.f};

    int mrow[2];
#pragma unroll
    for (int mt = 0; mt < 2; ++mt) {
        int r = row0 + mt * 16 + m;
        mrow[mt] = (r < n) ? r : (n - 1);       // clamp tail (dup row, store-guarded)
    }

#pragma unroll
    for (int t = 0; t < 4; ++t) {
        f16x8 xf[2];
#pragma unroll
        for (int mt = 0; mt < 2; ++mt) {
            if constexpr (XHALF) {
                xf[mt] = *(const f16x8*)((const f16*)Xv + (size_t)mrow[mt] * 128 + t * 32 + kg * 8);
            } else {
                const float* Xf = (const float*)Xv + (size_t)mrow[mt] * 128 + t * 32 + kg * 8;
                float4 p = *(const float4*)Xf;
                float4 q = *(const float4*)(Xf + 4);
                f16x8 h;
                h[0] = (f16)p.x; h[1] = (f16)p.y; h[2] = (f16)p.z; h[3] = (f16)p.w;
                h[4] = (f16)q.x; h[5] = (f16)q.y; h[6] = (f16)q.z; h[7] = (f16)q.w;
                xf[mt] = h;
            }
        }
#pragma unroll
        for (int mt = 0; mt < 2; ++mt)
#pragma unroll
            for (int ct = 0; ct < 4; ++ct)
                acc[mt][ct] = __builtin_amdgcn_mfma_f32_16x16x32_f16(
                    bw[ct][t], xf[mt], acc[mt][ct], 0, 0, 0);
    }

#pragma unroll
    for (int mt = 0; mt < 2; ++mt) {
        int row = row0 + mt * 16 + m;
        if (row >= n) continue;
        float dv = dinv[row];
#pragma unroll
        for (int ct = 0; ct < 4; ++ct) {
            f16x4 o;
#pragma unroll
            for (int r = 0; r < 4; ++r) o[r] = (f16)(acc[mt][ct][r] * dv);
            *(f16x4*)&Y[(size_t)row * 128 + ch * 64 + ct * 16 + kg * 4] = o;
        }
    }
}

__global__ __launch_bounds__(256) void gemm_mfma_h(const f16* __restrict__ X,
                                                   const f16x8* __restrict__ wf,
                                                   const float* __restrict__ dinv,
                                                   f16* __restrict__ Y, int n) {
    gemm_core<true>(X, wf, dinv, Y, n, blockIdx.x);
}

// GEMM1 (fp32 input) fused with XCD-sliced CSR fill in the surplus blocks.
__global__ __launch_bounds__(256) void gemm_fill(const float* __restrict__ X,
                                                 const f16x8* __restrict__ wf,
                                                 const float* __restrict__ dinv,
                                                 f16* __restrict__ Y, int n,
                                                 const int* __restrict__ src,
                                                 const int* __restrict__ dst,
                                                 int* __restrict__ cursor,
                                                 int* __restrict__ csr_src, int ne,
                                                 int gemmBlocks) {
    if ((int)blockIdx.x < gemmBlocks) {
        gemm_core<false>(X, wf, dinv, Y, n, blockIdx.x);
        return;
    }
    int fb = blockIdx.x - gemmBlocks;
    int slice = fb & 7;                 // bid residue ~ XCD; dst-space slice
    const int stride = 128 * 256;
    for (int e = (fb >> 3) * 256 + (int)threadIdx.x; e < ne; e += stride) {
        int d = dst[e];
        int s = src[e];
        if (((d >> 14) & 7) == slice) {
            int pos = atomicAdd(&cursor[d], 1);
            csr_src[pos] = s;
        }
    }
}

__device__ __forceinline__ void addF16x8(float* __restrict__ a, f16x8 v) {
#pragma unroll
    for (int j = 0; j < 8; ++j) a[j] += (float)v[j];
}

// A[d,:] = fp16( relu( dinv[d]*(sum_{e in row d} Y[src,:] + Y[d,:]) + b ) )
// 16 lanes/node, 16 B per lane, fp32 accumulation, 4-deep pipelined gather.
__global__ __launch_bounds__(256) void agg_fused(const f16* __restrict__ Y,
                                                 const int* __restrict__ row_ptr,
                                                 const int* __restrict__ csr_src,
                                                 const float* __restrict__ dinv,
                                                 const float* __restrict__ b,
                                                 f16* __restrict__ A, int n) {
    int node = blockIdx.x * 16 + (threadIdx.x >> 4);
    if (node >= n) return;
    int lane = threadIdx.x & 15;
    int lo = lane * 8;
    int beg = row_ptr[node], end = row_ptr[node + 1];
    float acc[8] = {0.f, 0.f, 0.f, 0.f, 0.f, 0.f, 0.f, 0.f};
    addF16x8(acc, *(const f16x8*)&Y[(size_t)node * 128 + lo]);   // self loop
    int e = beg;
    for (; e + 4 <= end; e += 4) {
        int s0 = csr_src[e + 0];
        int s1 = csr_src[e + 1];
        int s2 = csr_src[e + 2];
        int s3 = csr_src[e + 3];
        f16x8 v0 = *(const f16x8*)&Y[(size_t)s0 * 128 + lo];
        f16x8 v1 = *(const f16x8*)&Y[(size_t)s1 * 128 + lo];
        f16x8 v2 = *(const f16x8*)&Y[(size_t)s2 * 128 + lo];
        f16x8 v3 = *(const f16x8*)&Y[(size_t)s3 * 128 + lo];
        addF16x8(acc, v0); addF16x8(acc, v1);
        addF16x8(acc, v2); addF16x8(acc, v3);
    }
    for (; e < end; ++e) {
        int s = csr_src[e];
        addF16x8(acc, *(const f16x8*)&Y[(size_t)s * 128 + lo]);
    }
    float dn = dinv[node];
    f16x8 o;
#pragma unroll
    for (int j = 0; j < 8; ++j) o[j] = (f16)fmaxf(fmaf(acc[j], dn, b[lo + j]), 0.f);
    *(f16x8*)&A[(size_t)node * 128 + lo] = o;
}

__device__ __forceinline__ int lower_bound(const int* __restrict__ a, int n, int key) {
    int lo = 0, hi = n;
    while (lo < hi) {
        int mid = (lo + hi) >> 1;
        if (a[mid] < key) lo = mid + 1; else hi = mid;
    }
    return lo;
}

__global__ __launch_bounds__(128) void pool_kernel(const f16* __restrict__ H,
                                                   const int* __restrict__ batch,
                                                   float* __restrict__ pooled, int n) {
    int g = blockIdx.x;
    int beg = lower_bound(batch, n, g);
    int end = lower_bound(batch, n, g + 1);
    int f = threadIdx.x;
    float s = 0.f, m = -INFINITY;
    for (int i = beg; i < end; ++i) {
        float v = (float)H[(size_t)i * 128 + f];
        s += v;
        m = fmaxf(m, v);
    }
    float cnt = (float)(end - beg);
    pooled[(size_t)g * 256 + f]       = s / fmaxf(cnt, 1.0f);
    pooled[(size_t)g * 256 + 128 + f] = m;
}

__global__ __launch_bounds__(64) void fc_kernel(const float* __restrict__ pooled,
                                                const float* __restrict__ fcW,
                                                const float* __restrict__ fcb,
                                                float* __restrict__ out, int C) {
    int g = blockIdx.x;
    __shared__ float p[256];
    int t = threadIdx.x;
    for (int k = t; k < 256; k += 64) p[k] = pooled[(size_t)g * 256 + k];
    __syncthreads();
    if (t < C) {
        float acc = fcb[t];
        for (int k = 0; k < 256; ++k) acc = fmaf(p[k], fcW[k * C + t], acc);
        out[(size_t)g * C + t] = acc;
    }
}

extern "C" void kernel_launch(void* const* d_in, const int* in_sizes, int n_in,
                              void* d_out, int out_size, void* d_ws, size_t ws_size,
                              hipStream_t stream) {
    const float* x     = (const float*)d_in[0];
    const int*   ei    = (const int*)d_in[1];
    const int*   batch = (const int*)d_in[2];
    const float* W1    = (const float*)d_in[3];
    const float* b1    = (const float*)d_in[4];
    const float* W2    = (const float*)d_in[5];
    const float* b2    = (const float*)d_in[6];
    const float* W3    = (const float*)d_in[7];
    const float* b3    = (const float*)d_in[8];
    const float* fcW   = (const float*)d_in[9];
    const float* fcb   = (const float*)d_in[10];

    const int N = in_sizes[0] / 128;
    const int E = in_sizes[1] / 2;
    const int C = in_sizes[10];
    const int G = out_size / C;
    float* out = (float*)d_out;

    // workspace layout
    f16*   Yh       = (f16*)d_ws;                         // [N*128]
    f16*   Ah       = Yh + (size_t)N * 128;               // [N*128]
    f16x8* wf       = (f16x8*)(Ah + (size_t)N * 128);     // [3*2048] frag-packed W
    float* dinv     = (float*)(wf + 3 * 2048);            // [N]
    float* pooled   = dinv + N;                           // [G*256]
    int*   counts   = (int*)(pooled + (size_t)G * 256);   // [N]
    int*   partials = counts + N;                         // [1024]
    int*   row_ptr  = partials + 1024;                    // [N+4]
    int*   cursor   = row_ptr + N + 4;                    // [N]
    int*   csr_src  = cursor + N;                         // [E]

    const int* src = ei;
    const int* dst = ei + E;

    const int scanBlocks = (N + 1023) / 1024;
    const int gemmBlocks = (N + 63) / 64;
    const int fillBlocks = 1024;

    // --- prep (W frag-pack + sliced hist) -> scan -> [gemm1 + sliced fill] ---
    hipMemsetAsync(counts, 0, (size_t)N * sizeof(int), stream);
    prep_kernel<<<24 + 1024, 256, 0, stream>>>(W1, W2, W3, wf, dst, counts, E);
    scan_part<<<scanBlocks, 256, 0, stream>>>(counts, partials, N);
    scan_partials<<<1, 1024, 0, stream>>>(partials, scanBlocks);
    scan_apply<<<scanBlocks, 256, 0, stream>>>(counts, partials, row_ptr, cursor, dinv, N, E);

    // layer 1: MFMA gemm (fp32 in, fp16 out) fused with sliced CSR fill
    gemm_fill<<<gemmBlocks + fillBlocks, 256, 0, stream>>>(
        x, wf, dinv, Yh, N, src, dst, cursor, csr_src, E, gemmBlocks);
    agg_fused<<<(N + 15) / 16, 256, 0, stream>>>(Yh, row_ptr, csr_src, dinv, b1, Ah, N);

    // layers 2, 3 (fp16 in, fp16 out)
    gemm_mfma_h<<<gemmBlocks, 256, 0, stream>>>(Ah, wf + 2048, dinv, Yh, N);
    agg_fused<<<(N + 15) / 16, 256, 0, stream>>>(Yh, row_ptr, csr_src, dinv, b2, Ah, N);
    gemm_mfma_h<<<gemmBlocks, 256, 0, stream>>>(Ah, wf + 4096, dinv, Yh, N);
    agg_fused<<<(N + 15) / 16, 256, 0, stream>>>(Yh, row_ptr, csr_src, dinv, b3, Ah, N);

    pool_kernel<<<G, 128, 0, stream>>>(Ah, batch, pooled, N);
    fc_kernel<<<G, 64, 0, stream>>>(pooled, fcW, fcb, out, C);
}

// Round 7
// 407.207 us; speedup vs baseline: 22.1441x; 1.1614x over previous
//
#include <hip/hip_runtime.h>
#include <hip/hip_fp16.h>

// ---------------------------------------------------------------------------
// GCN graph classification: 3x GCNConv(128->128) + mean/max pool + FC(256->10)
// Round 7: radix-by-dst CSR build (stripe hist -> bucket pairs -> LDS-cursor
//          place), replacing the atomic-cursor fill entirely. 64-lane/node
//          divergence-free agg with 8-deep scalarized gather. Vectorized pool.
// ---------------------------------------------------------------------------

typedef _Float16 f16;
typedef f16 f16x8 __attribute__((ext_vector_type(8)));
typedef f16 f16x4 __attribute__((ext_vector_type(4)));
typedef f16 f16x2 __attribute__((ext_vector_type(2)));
typedef float f32x4 __attribute__((ext_vector_type(4)));

#define STRIPE_BITS 11
#define STRIPE_SZ 2048

// --- prep: pack W1/W2/W3 into MFMA A-fragment order + stripe histogram -----
// wf slot (ch,ct,t,lane): 8 halves j -> W[k=t*32+(lane>>4)*8+j][c=ch*64+ct*16+(lane&15)]
__global__ __launch_bounds__(256) void prep_kernel(const float* __restrict__ W1,
                                                   const float* __restrict__ W2,
                                                   const float* __restrict__ W3,
                                                   f16x8* __restrict__ wf,
                                                   const int* __restrict__ dst,
                                                   int* __restrict__ scnt,
                                                   int ne, int ns) {
    int bid = blockIdx.x;
    int t = threadIdx.x;
    if (bid < 24) {
        int layer = bid >> 3;
        const float* W = (layer == 0) ? W1 : (layer == 1 ? W2 : W3);
        int tid2 = (bid & 7) * 256 + t;   // 0..2047
        int ch = tid2 >> 10;
        int ct = (tid2 >> 8) & 3;
        int tt = (tid2 >> 6) & 3;
        int l  = tid2 & 63;
        int c  = ch * 64 + ct * 16 + (l & 15);
        int k0 = tt * 32 + ((l >> 4) << 3);
        f16x8 v;
#pragma unroll
        for (int j = 0; j < 8; ++j) v[j] = (f16)W[(size_t)(k0 + j) * 128 + c];
        wf[layer * 2048 + tid2] = v;
        return;
    }
    // stripe histogram: LDS-local counts, 49 global atomics per block
    __shared__ int h[64];
    if (t < 64) h[t] = 0;
    __syncthreads();
    const int stride = 512 * 256;
    for (int e = (bid - 24) * 256 + t; e < ne; e += stride)
        atomicAdd(&h[dst[e] >> STRIPE_BITS], 1);
    __syncthreads();
    if (t < ns && h[t]) atomicAdd(&scnt[t], h[t]);
}

// exclusive scan over <=64 stripe counts (single wave)
__global__ __launch_bounds__(64) void stripe_scan(const int* __restrict__ scnt,
                                                  int* __restrict__ sbase,
                                                  int* __restrict__ scursor, int ns) {
    int t = threadIdx.x;
    int v = (t < ns) ? scnt[t] : 0;
    int sc = v;
#pragma unroll
    for (int off = 1; off < 64; off <<= 1) {
        int u = __shfl_up(sc, off, 64);
        if (t >= off) sc += u;
    }
    int excl = sc - v;
    if (t < ns) { sbase[t] = excl; scursor[t] = excl; }
    if (t == ns - 1) sbase[ns] = sc;
}

// pass 1: bucket (src,dst) pairs into contiguous stripe regions of ebuf.
// Per 1024-edge batch: LDS rank by stripe -> one bulk global atomic per
// stripe -> writes land in small contiguous windows (low amplification).
__global__ __launch_bounds__(256) void bucket_pairs(const int* __restrict__ src,
                                                    const int* __restrict__ dst,
                                                    int* __restrict__ scursor,
                                                    uint2* __restrict__ ebuf, int ne) {
    __shared__ int h[64];
    __shared__ int goff[64];
    int t = threadIdx.x;
    for (int base = blockIdx.x * 1024; base < ne; base += gridDim.x * 1024) {
        __syncthreads();
        if (t < 64) h[t] = 0;
        __syncthreads();
        int sv[4], dv[4], rk[4], st[4];
        bool ok[4];
#pragma unroll
        for (int u = 0; u < 4; ++u) {
            int e = base + u * 256 + t;
            ok[u] = e < ne;
            sv[u] = ok[u] ? src[e] : 0;
            dv[u] = ok[u] ? dst[e] : 0;
            st[u] = dv[u] >> STRIPE_BITS;
            rk[u] = ok[u] ? atomicAdd(&h[st[u]], 1) : 0;
        }
        __syncthreads();
        if (t < 64) { int c = h[t]; goff[t] = c ? atomicAdd(&scursor[t], c) : 0; }
        __syncthreads();
#pragma unroll
        for (int u = 0; u < 4; ++u)
            if (ok[u]) {
                uint2 pr; pr.x = (unsigned)sv[u]; pr.y = (unsigned)dv[u];
                ebuf[(size_t)goff[st[u]] + rk[u]] = pr;
            }
    }
}

// pass 2: one block per stripe. LDS hist(2048) -> block scan -> row_ptr/dinv
// (coalesced) -> place csr_src via LDS cursors (writes confined to the
// stripe's ~128KB L2-resident window).
__global__ __launch_bounds__(256) void place_kernel(const uint2* __restrict__ ebuf,
                                                    const int* __restrict__ sbase,
                                                    int* __restrict__ row_ptr,
                                                    int* __restrict__ csr,
                                                    float* __restrict__ dinv,
                                                    int n, int ne, int ns) {
    __shared__ int cnt[STRIPE_SZ];
    __shared__ int cur[STRIPE_SZ];
    __shared__ int wsum[4];
    int s = blockIdx.x;
    int t = threadIdx.x;
    int node0 = s << STRIPE_BITS;
    int ebeg = sbase[s], eend = sbase[s + 1];
    for (int i = t; i < STRIPE_SZ; i += 256) cnt[i] = 0;
    __syncthreads();
    for (int p = ebeg + t; p < eend; p += 256)
        atomicAdd(&cnt[ebuf[p].y & (STRIPE_SZ - 1)], 1);
    __syncthreads();
    // block scan of 2048 counts (8 per thread)
    int c[8]; int ts = 0;
#pragma unroll
    for (int j = 0; j < 8; ++j) { c[j] = cnt[t * 8 + j]; ts += c[j]; }
    int lane = t & 63, wid = t >> 6;
    int sc = ts;
#pragma unroll
    for (int off = 1; off < 64; off <<= 1) {
        int u = __shfl_up(sc, off, 64);
        if (lane >= off) sc += u;
    }
    if (lane == 63) wsum[wid] = sc;
    __syncthreads();
    if (t == 0) { int r = 0; for (int i = 0; i < 4; ++i) { int x = wsum[i]; wsum[i] = r; r += x; } }
    __syncthreads();
    int run = wsum[wid] + sc - ts;
#pragma unroll
    for (int j = 0; j < 8; ++j) {
        int node = node0 + t * 8 + j;
        cur[t * 8 + j] = run;
        if (node < n) {
            row_ptr[node] = ebeg + run;
            dinv[node] = 1.0f / sqrtf((float)c[j] + 1.0f);
        }
        run += c[j];
    }
    if (s == ns - 1 && t == 255) row_ptr[n] = ne;
    __syncthreads();
    for (int p = ebeg + t; p < eend; p += 1024) {
#pragma unroll
        for (int u = 0; u < 4; ++u) {
            int pp = p + u * 256;
            if (pp < eend) {
                uint2 pr = ebuf[pp];
                int r = atomicAdd(&cur[pr.y & (STRIPE_SZ - 1)], 1);
                csr[ebeg + r] = (int)pr.x;
            }
        }
    }
}

// --- MFMA GEMM core: Y[m,:] = fp16( dinv[m] * (X[m,:] @ W) ) ---------------
template <bool XHALF>
__device__ __forceinline__ void gemm_core(const void* __restrict__ Xv,
                                          const f16x8* __restrict__ wf,
                                          const float* __restrict__ dinv,
                                          f16* __restrict__ Y, int n, int bid) {
    const int tid = threadIdx.x;
    const int l = tid & 63;
    const int w = tid >> 6;
    const int ch = w & 1;
    const int row0 = bid * 64 + (w >> 1) * 32;
    const int m = l & 15;
    const int kg = l >> 4;

    f16x8 bw[4][4];
#pragma unroll
    for (int ct = 0; ct < 4; ++ct)
#pragma unroll
        for (int t = 0; t < 4; ++t)
            bw[ct][t] = wf[((ch * 4 + ct) * 4 + t) * 64 + l];

    f32x4 acc[2][4];
#pragma unroll
    for (int mt = 0; mt < 2; ++mt)
#pragma unroll
        for (int ct = 0; ct < 4; ++ct) acc[mt][ct] = (f32x4){0.f, 0.f, 0.f, 0.f};

    int mrow[2];
#pragma unroll
    for (int mt = 0; mt < 2; ++mt) {
        int r = row0 + mt * 16 + m;
        mrow[mt] = (r < n) ? r : (n - 1);
    }

#pragma unroll
    for (int t = 0; t < 4; ++t) {
        f16x8 xf[2];
#pragma unroll
        for (int mt = 0; mt < 2; ++mt) {
            if constexpr (XHALF) {
                xf[mt] = *(const f16x8*)((const f16*)Xv + (size_t)mrow[mt] * 128 + t * 32 + kg * 8);
            } else {
                const float* Xf = (const float*)Xv + (size_t)mrow[mt] * 128 + t * 32 + kg * 8;
                float4 p = *(const float4*)Xf;
                float4 q = *(const float4*)(Xf + 4);
                f16x8 h;
                h[0] = (f16)p.x; h[1] = (f16)p.y; h[2] = (f16)p.z; h[3] = (f16)p.w;
                h[4] = (f16)q.x; h[5] = (f16)q.y; h[6] = (f16)q.z; h[7] = (f16)q.w;
                xf[mt] = h;
            }
        }
#pragma unroll
        for (int mt = 0; mt < 2; ++mt)
#pragma unroll
            for (int ct = 0; ct < 4; ++ct)
                acc[mt][ct] = __builtin_amdgcn_mfma_f32_16x16x32_f16(
                    bw[ct][t], xf[mt], acc[mt][ct], 0, 0, 0);
    }

#pragma unroll
    for (int mt = 0; mt < 2; ++mt) {
        int row = row0 + mt * 16 + m;
        if (row >= n) continue;
        float dv = dinv[row];
#pragma unroll
        for (int ct = 0; ct < 4; ++ct) {
            f16x4 o;
#pragma unroll
            for (int r = 0; r < 4; ++r) o[r] = (f16)(acc[mt][ct][r] * dv);
            *(f16x4*)&Y[(size_t)row * 128 + ch * 64 + ct * 16 + kg * 4] = o;
        }
    }
}

__global__ __launch_bounds__(256) void gemm_mfma_h(const f16* __restrict__ X,
                                                   const f16x8* __restrict__ wf,
                                                   const float* __restrict__ dinv,
                                                   f16* __restrict__ Y, int n) {
    gemm_core<true>(X, wf, dinv, Y, n, blockIdx.x);
}

__global__ __launch_bounds__(256) void gemm_mfma_f(const float* __restrict__ X,
                                                   const f16x8* __restrict__ wf,
                                                   const float* __restrict__ dinv,
                                                   f16* __restrict__ Y, int n) {
    gemm_core<false>(X, wf, dinv, Y, n, blockIdx.x);
}

// A[d,:] = fp16( relu( dinv[d]*(sum_{e in row d} Y[src,:] + Y[d,:]) + b ) )
// 64 lanes per node (f16x2 each): zero intra-wave divergence; 8-deep
// clamp-padded gather with scalarized (SGPR) row indices.
__global__ __launch_bounds__(256) void agg_fused(const f16* __restrict__ Y,
                                                 const int* __restrict__ row_ptr,
                                                 const int* __restrict__ csr,
                                                 const float* __restrict__ dinv,
                                                 const float* __restrict__ b,
                                                 f16* __restrict__ A, int n) {
    int node = (int)((blockIdx.x * 256 + threadIdx.x) >> 6);
    node = __builtin_amdgcn_readfirstlane(node);
    if (node >= n) return;
    int lane = threadIdx.x & 63;
    const f16x2* Yv = (const f16x2*)Y;
    size_t rowOff = (size_t)node * 64;
    f16x2 sv = Yv[rowOff + lane];           // self loop
    float ax = (float)sv[0], ay = (float)sv[1];
    int beg = row_ptr[node], end = row_ptr[node + 1];
    for (int e = beg; e < end; e += 8) {
        int idx[8];
        float w[8];
#pragma unroll
        for (int u = 0; u < 8; ++u) {
            int ee = e + u;
            bool live = ee < end;
            int cl = live ? ee : end - 1;
            int s = csr[cl];
            idx[u] = __builtin_amdgcn_readfirstlane(live ? s : node);
            w[u] = live ? 1.f : 0.f;
        }
#pragma unroll
        for (int u = 0; u < 8; ++u) {
            f16x2 v = Yv[(size_t)idx[u] * 64 + lane];
            ax = fmaf(w[u], (float)v[0], ax);
            ay = fmaf(w[u], (float)v[1], ay);
        }
    }
    float dn = dinv[node];
    float2 bb = *(const float2*)&b[2 * lane];
    f16x2 o;
    o[0] = (f16)fmaxf(fmaf(ax, dn, bb.x), 0.f);
    o[1] = (f16)fmaxf(fmaf(ay, dn, bb.y), 0.f);
    *((f16x2*)A + rowOff + lane) = o;
}

__device__ __forceinline__ int lower_bound(const int* __restrict__ a, int n, int key) {
    int lo = 0, hi = n;
    while (lo < hi) {
        int mid = (lo + hi) >> 1;
        if (a[mid] < key) lo = mid + 1; else hi = mid;
    }
    return lo;
}

// block per graph; 4 node-parallel groups x 64 lanes x f16x2.
__global__ __launch_bounds__(256) void pool_kernel(const f16* __restrict__ H,
                                                   const int* __restrict__ batch,
                                                   float* __restrict__ pooled, int n) {
    __shared__ float red[3][64][4];
    int g = blockIdx.x;
    int beg = lower_bound(batch, n, g);
    int end = lower_bound(batch, n, g + 1);
    int t = threadIdx.x, sub = t >> 6, lane = t & 63;
    const f16x2* Hv = (const f16x2*)H;
    float sx = 0.f, sy = 0.f, mx = -INFINITY, my = -INFINITY;
    for (int i = beg + sub; i < end; i += 4) {
        f16x2 v = Hv[(size_t)i * 64 + lane];
        float a = (float)v[0], c = (float)v[1];
        sx += a; sy += c;
        mx = fmaxf(mx, a); my = fmaxf(my, c);
    }
    if (sub) {
        red[sub - 1][lane][0] = sx; red[sub - 1][lane][1] = sy;
        red[sub - 1][lane][2] = mx; red[sub - 1][lane][3] = my;
    }
    __syncthreads();
    if (sub == 0) {
#pragma unroll
        for (int k = 0; k < 3; ++k) {
            sx += red[k][lane][0]; sy += red[k][lane][1];
            mx = fmaxf(mx, red[k][lane][2]); my = fmaxf(my, red[k][lane][3]);
        }
        float cnt = fmaxf((float)(end - beg), 1.0f);
        pooled[(size_t)g * 256 + 2 * lane]       = sx / cnt;
        pooled[(size_t)g * 256 + 2 * lane + 1]   = sy / cnt;
        pooled[(size_t)g * 256 + 128 + 2 * lane]     = mx;
        pooled[(size_t)g * 256 + 128 + 2 * lane + 1] = my;
    }
}

__global__ __launch_bounds__(64) void fc_kernel(const float* __restrict__ pooled,
                                                const float* __restrict__ fcW,
                                                const float* __restrict__ fcb,
                                                float* __restrict__ out, int C) {
    int g = blockIdx.x;
    __shared__ float p[256];
    int t = threadIdx.x;
    for (int k = t; k < 256; k += 64) p[k] = pooled[(size_t)g * 256 + k];
    __syncthreads();
    if (t < C) {
        float acc = fcb[t];
        for (int k = 0; k < 256; ++k) acc = fmaf(p[k], fcW[k * C + t], acc);
        out[(size_t)g * C + t] = acc;
    }
}

extern "C" void kernel_launch(void* const* d_in, const int* in_sizes, int n_in,
                              void* d_out, int out_size, void* d_ws, size_t ws_size,
                              hipStream_t stream) {
    const float* x     = (const float*)d_in[0];
    const int*   ei    = (const int*)d_in[1];
    const int*   batch = (const int*)d_in[2];
    const float* W1    = (const float*)d_in[3];
    const float* b1    = (const float*)d_in[4];
    const float* W2    = (const float*)d_in[5];
    const float* b2    = (const float*)d_in[6];
    const float* W3    = (const float*)d_in[7];
    const float* b3    = (const float*)d_in[8];
    const float* fcW   = (const float*)d_in[9];
    const float* fcb   = (const float*)d_in[10];

    const int N = in_sizes[0] / 128;
    const int E = in_sizes[1] / 2;
    const int C = in_sizes[10];
    const int G = out_size / C;
    const int NS = (N + STRIPE_SZ - 1) >> STRIPE_BITS;
    float* out = (float*)d_out;

    // workspace layout
    f16*   Yh      = (f16*)d_ws;                          // [N*128]
    f16*   Ah      = Yh + (size_t)N * 128;                // [N*128]
    f16x8* wf      = (f16x8*)(Ah + (size_t)N * 128);      // [3*2048]
    float* dinv    = (float*)(wf + 3 * 2048);             // [N]
    float* pooled  = dinv + N;                            // [G*256]
    int*   row_ptr = (int*)(pooled + (size_t)G * 256);    // [N+8]
    int*   csr_src = row_ptr + N + 8;                     // [E]
    uint2* ebuf    = (uint2*)(csr_src + E);               // [E]
    int*   scnt    = (int*)(ebuf + E);                    // [64]
    int*   sbase   = scnt + 64;                           // [72]
    int*   scursor = sbase + 72;                          // [64]

    const int* src = ei;
    const int* dst = ei + E;

    // --- radix CSR build ---
    hipMemsetAsync(scnt, 0, 64 * sizeof(int), stream);
    prep_kernel<<<24 + 512, 256, 0, stream>>>(W1, W2, W3, wf, dst, scnt, E, NS);
    stripe_scan<<<1, 64, 0, stream>>>(scnt, sbase, scursor, NS);
    bucket_pairs<<<512, 256, 0, stream>>>(src, dst, scursor, ebuf, E);
    place_kernel<<<NS, 256, 0, stream>>>(ebuf, sbase, row_ptr, csr_src, dinv, N, E, NS);

    const int gemmBlocks = (N + 63) / 64;
    const int aggBlocks = (int)(((long long)N * 64 + 255) / 256);

    gemm_mfma_f<<<gemmBlocks, 256, 0, stream>>>(x, wf, dinv, Yh, N);
    agg_fused<<<aggBlocks, 256, 0, stream>>>(Yh, row_ptr, csr_src, dinv, b1, Ah, N);
    gemm_mfma_h<<<gemmBlocks, 256, 0, stream>>>(Ah, wf + 2048, dinv, Yh, N);
    agg_fused<<<aggBlocks, 256, 0, stream>>>(Yh, row_ptr, csr_src, dinv, b2, Ah, N);
    gemm_mfma_h<<<gemmBlocks, 256, 0, stream>>>(Ah, wf + 4096, dinv, Yh, N);
    agg_fused<<<aggBlocks, 256, 0, stream>>>(Yh, row_ptr, csr_src, dinv, b3, Ah, N);

    pool_kernel<<<G, 256, 0, stream>>>(Ah, batch, pooled, N);
    fc_kernel<<<G, 64, 0, stream>>>(pooled, fcW, fcb, out, C);
}

// Round 8
// 325.315 us; speedup vs baseline: 27.7184x; 1.2517x over previous
//
#include <hip/hip_runtime.h>
#include <hip/hip_fp16.h>

// ---------------------------------------------------------------------------
// GCN graph classification: 3x GCNConv(128->128) + mean/max pool + FC(256->10)
// Round 8: deterministic 2-pass radix CSR build at 256-node bins (391-way
//          parallel place, zero global cursor atomics, packed u32 pairs).
//          MFMA GEMMs + 64-lane/node gather agg as before.
// ---------------------------------------------------------------------------

typedef _Float16 f16;
typedef f16 f16x8 __attribute__((ext_vector_type(8)));
typedef f16 f16x4 __attribute__((ext_vector_type(4)));
typedef f16 f16x2 __attribute__((ext_vector_type(2)));
typedef float f32x4 __attribute__((ext_vector_type(4)));

#define BIN_BITS 8
#define BINSZ 256
#define CB 256              // chunk blocks for bucket passes
#define SRC_BITS 17         // N < 131072

// --- prep: W frag-pack (24 blocks) + per-chunk bin histogram (256 blocks) --
__global__ __launch_bounds__(256) void prep_count(const float* __restrict__ W1,
                                                  const float* __restrict__ W2,
                                                  const float* __restrict__ W3,
                                                  f16x8* __restrict__ wf,
                                                  const int* __restrict__ dst,
                                                  int* __restrict__ bcnt,
                                                  int ne, int nb, int chunk) {
    int bid = blockIdx.x;
    int t = threadIdx.x;
    if (bid < 24) {
        int layer = bid >> 3;
        const float* W = (layer == 0) ? W1 : (layer == 1 ? W2 : W3);
        int tid2 = (bid & 7) * 256 + t;   // 0..2047
        int ch = tid2 >> 10;
        int ct = (tid2 >> 8) & 3;
        int tt = (tid2 >> 6) & 3;
        int l  = tid2 & 63;
        int c  = ch * 64 + ct * 16 + (l & 15);
        int k0 = tt * 32 + ((l >> 4) << 3);
        f16x8 v;
#pragma unroll
        for (int j = 0; j < 8; ++j) v[j] = (f16)W[(size_t)(k0 + j) * 128 + c];
        wf[layer * 2048 + tid2] = v;
        return;
    }
    __shared__ int h[512];
    int b = bid - 24;
    for (int i = t; i < 512; i += 256) h[i] = 0;
    __syncthreads();
    int e0 = b * chunk, e1 = min(ne, e0 + chunk);
    for (int e = e0 + t; e < e1; e += 256)
        atomicAdd(&h[dst[e] >> BIN_BITS], 1);
    __syncthreads();
    for (int i = t; i < nb; i += 256) bcnt[(size_t)b * 512 + i] = h[i];
}

// per-bin exclusive scan over the 256 chunk-blocks; rel written in place.
__global__ __launch_bounds__(256) void binscan(int* __restrict__ bcnt,
                                               int* __restrict__ tot, int nb) {
    __shared__ int ws[4];
    int bin = blockIdx.x;
    int t = threadIdx.x;
    int v = bcnt[(size_t)t * 512 + bin];
    int lane = t & 63, wid = t >> 6;
    int sc = v;
#pragma unroll
    for (int off = 1; off < 64; off <<= 1) {
        int u = __shfl_up(sc, off, 64);
        if (lane >= off) sc += u;
    }
    if (lane == 63) ws[wid] = sc;
    __syncthreads();
    if (t == 0) { int r = 0; for (int i = 0; i < 4; ++i) { int x = ws[i]; ws[i] = r; r += x; } }
    __syncthreads();
    int excl = ws[wid] + sc - v;
    bcnt[(size_t)t * 512 + bin] = excl;
    if (t == 255) tot[bin] = excl + v;
}

// exclusive scan of <=512 bin totals -> base[]; also base[nb]=ne, row_ptr[n]=ne
__global__ __launch_bounds__(512) void s512scan(const int* __restrict__ tot,
                                                int* __restrict__ base,
                                                int* __restrict__ row_ptr,
                                                int nb, int n, int ne) {
    __shared__ int ws[8];
    int t = threadIdx.x;
    int v = (t < nb) ? tot[t] : 0;
    int lane = t & 63, wid = t >> 6;
    int sc = v;
#pragma unroll
    for (int off = 1; off < 64; off <<= 1) {
        int u = __shfl_up(sc, off, 64);
        if (lane >= off) sc += u;
    }
    if (lane == 63) ws[wid] = sc;
    __syncthreads();
    if (t == 0) { int r = 0; for (int i = 0; i < 8; ++i) { int x = ws[i]; ws[i] = r; r += x; } }
    __syncthreads();
    int excl = ws[wid] + sc - v;
    if (t < nb) base[t] = excl;
    if (t == 0) { base[nb] = ne; row_ptr[n] = ne; }
}

// pass 2: re-stream edges, place packed (src | local<<SRC_BITS) into the
// bin-grouped ebuf at base[bin] + rel[block][bin] + LDS-rank. No global atomics.
__global__ __launch_bounds__(256) void bucket_place(const int* __restrict__ src,
                                                    const int* __restrict__ dst,
                                                    const int* __restrict__ base,
                                                    const int* __restrict__ bcnt,
                                                    unsigned* __restrict__ ebuf,
                                                    int ne, int nb, int chunk) {
    __shared__ int cur[512];
    __shared__ int rel[512];
    int b = blockIdx.x;
    int t = threadIdx.x;
    for (int i = t; i < 512; i += 256) {
        cur[i] = 0;
        rel[i] = (i < nb) ? (base[i] + bcnt[(size_t)b * 512 + i]) : 0;
    }
    __syncthreads();
    int e0 = b * chunk, e1 = min(ne, e0 + chunk);
    for (int e = e0 + t; e < e1; e += 256) {
        int d = dst[e];
        int s = src[e];
        int bin = d >> BIN_BITS;
        int rank = atomicAdd(&cur[bin], 1);
        ebuf[(size_t)rel[bin] + rank] = (unsigned)s | ((unsigned)(d & (BINSZ - 1)) << SRC_BITS);
    }
}

// one block per bin: LDS hist -> scan -> row_ptr/dinv -> LDS-cursor place.
__global__ __launch_bounds__(256) void place_kernel(const unsigned* __restrict__ ebuf,
                                                    const int* __restrict__ base,
                                                    int* __restrict__ row_ptr,
                                                    int* __restrict__ csr,
                                                    float* __restrict__ dinv, int n) {
    __shared__ int hist[BINSZ];
    __shared__ int cur[BINSZ];
    __shared__ int ws[4];
    int bin = blockIdx.x;
    int t = threadIdx.x;
    int node0 = bin << BIN_BITS;
    int ebeg = base[bin], eend = base[bin + 1];
    hist[t] = 0;
    __syncthreads();
    for (int p = ebeg + t; p < eend; p += 256)
        atomicAdd(&hist[ebuf[p] >> SRC_BITS], 1);
    __syncthreads();
    int c = hist[t];
    int lane = t & 63, wid = t >> 6;
    int sc = c;
#pragma unroll
    for (int off = 1; off < 64; off <<= 1) {
        int u = __shfl_up(sc, off, 64);
        if (lane >= off) sc += u;
    }
    if (lane == 63) ws[wid] = sc;
    __syncthreads();
    if (t == 0) { int r = 0; for (int i = 0; i < 4; ++i) { int x = ws[i]; ws[i] = r; r += x; } }
    __syncthreads();
    int excl = ws[wid] + sc - c;
    int node = node0 + t;
    if (node < n) {
        row_ptr[node] = ebeg + excl;
        dinv[node] = 1.0f / sqrtf((float)c + 1.0f);
    }
    cur[t] = excl;
    __syncthreads();
    for (int p = ebeg + t; p < eend; p += 256) {
        unsigned v = ebuf[p];
        int local = v >> SRC_BITS;
        int r = atomicAdd(&cur[local], 1);
        csr[ebeg + r] = (int)(v & ((1u << SRC_BITS) - 1));
    }
}

// --- MFMA GEMM core: Y[m,:] = fp16( dinv[m] * (X[m,:] @ W) ) ---------------
template <bool XHALF>
__device__ __forceinline__ void gemm_core(const void* __restrict__ Xv,
                                          const f16x8* __restrict__ wf,
                                          const float* __restrict__ dinv,
                                          f16* __restrict__ Y, int n, int bid) {
    const int tid = threadIdx.x;
    const int l = tid & 63;
    const int w = tid >> 6;
    const int ch = w & 1;
    const int row0 = bid * 64 + (w >> 1) * 32;
    const int m = l & 15;
    const int kg = l >> 4;

    f16x8 bw[4][4];
#pragma unroll
    for (int ct = 0; ct < 4; ++ct)
#pragma unroll
        for (int t = 0; t < 4; ++t)
            bw[ct][t] = wf[((ch * 4 + ct) * 4 + t) * 64 + l];

    f32x4 acc[2][4];
#pragma unroll
    for (int mt = 0; mt < 2; ++mt)
#pragma unroll
        for (int ct = 0; ct < 4; ++ct) acc[mt][ct] = (f32x4){0.f, 0.f, 0.f, 0.f};

    int mrow[2];
#pragma unroll
    for (int mt = 0; mt < 2; ++mt) {
        int r = row0 + mt * 16 + m;
        mrow[mt] = (r < n) ? r : (n - 1);
    }

#pragma unroll
    for (int t = 0; t < 4; ++t) {
        f16x8 xf[2];
#pragma unroll
        for (int mt = 0; mt < 2; ++mt) {
            if constexpr (XHALF) {
                xf[mt] = *(const f16x8*)((const f16*)Xv + (size_t)mrow[mt] * 128 + t * 32 + kg * 8);
            } else {
                const float* Xf = (const float*)Xv + (size_t)mrow[mt] * 128 + t * 32 + kg * 8;
                float4 p = *(const float4*)Xf;
                float4 q = *(const float4*)(Xf + 4);
                f16x8 h;
                h[0] = (f16)p.x; h[1] = (f16)p.y; h[2] = (f16)p.z; h[3] = (f16)p.w;
                h[4] = (f16)q.x; h[5] = (f16)q.y; h[6] = (f16)q.z; h[7] = (f16)q.w;
                xf[mt] = h;
            }
        }
#pragma unroll
        for (int mt = 0; mt < 2; ++mt)
#pragma unroll
            for (int ct = 0; ct < 4; ++ct)
                acc[mt][ct] = __builtin_amdgcn_mfma_f32_16x16x32_f16(
                    bw[ct][t], xf[mt], acc[mt][ct], 0, 0, 0);
    }

#pragma unroll
    for (int mt = 0; mt < 2; ++mt) {
        int row = row0 + mt * 16 + m;
        if (row >= n) continue;
        float dv = dinv[row];
#pragma unroll
        for (int ct = 0; ct < 4; ++ct) {
            f16x4 o;
#pragma unroll
            for (int r = 0; r < 4; ++r) o[r] = (f16)(acc[mt][ct][r] * dv);
            *(f16x4*)&Y[(size_t)row * 128 + ch * 64 + ct * 16 + kg * 4] = o;
        }
    }
}

__global__ __launch_bounds__(256) void gemm_mfma_h(const f16* __restrict__ X,
                                                   const f16x8* __restrict__ wf,
                                                   const float* __restrict__ dinv,
                                                   f16* __restrict__ Y, int n) {
    gemm_core<true>(X, wf, dinv, Y, n, blockIdx.x);
}

__global__ __launch_bounds__(256) void gemm_mfma_f(const float* __restrict__ X,
                                                   const f16x8* __restrict__ wf,
                                                   const float* __restrict__ dinv,
                                                   f16* __restrict__ Y, int n) {
    gemm_core<false>(X, wf, dinv, Y, n, blockIdx.x);
}

// A[d,:] = fp16( relu( dinv[d]*(sum_{e in row d} Y[src,:] + Y[d,:]) + b ) )
// 64 lanes per node (f16x2 each), 8-deep clamp-padded scalarized gather.
__global__ __launch_bounds__(256) void agg_fused(const f16* __restrict__ Y,
                                                 const int* __restrict__ row_ptr,
                                                 const int* __restrict__ csr,
                                                 const float* __restrict__ dinv,
                                                 const float* __restrict__ b,
                                                 f16* __restrict__ A, int n) {
    int node = (int)((blockIdx.x * 256 + threadIdx.x) >> 6);
    node = __builtin_amdgcn_readfirstlane(node);
    if (node >= n) return;
    int lane = threadIdx.x & 63;
    const f16x2* Yv = (const f16x2*)Y;
    size_t rowOff = (size_t)node * 64;
    f16x2 sv = Yv[rowOff + lane];           // self loop
    float ax = (float)sv[0], ay = (float)sv[1];
    int beg = row_ptr[node], end = row_ptr[node + 1];
    for (int e = beg; e < end; e += 8) {
        int idx[8];
        float w[8];
#pragma unroll
        for (int u = 0; u < 8; ++u) {
            int ee = e + u;
            bool live = ee < end;
            int cl = live ? ee : end - 1;
            int s = csr[cl];
            idx[u] = __builtin_amdgcn_readfirstlane(live ? s : node);
            w[u] = live ? 1.f : 0.f;
        }
#pragma unroll
        for (int u = 0; u < 8; ++u) {
            f16x2 v = Yv[(size_t)idx[u] * 64 + lane];
            ax = fmaf(w[u], (float)v[0], ax);
            ay = fmaf(w[u], (float)v[1], ay);
        }
    }
    float dn = dinv[node];
    float2 bb = *(const float2*)&b[2 * lane];
    f16x2 o;
    o[0] = (f16)fmaxf(fmaf(ax, dn, bb.x), 0.f);
    o[1] = (f16)fmaxf(fmaf(ay, dn, bb.y), 0.f);
    *((f16x2*)A + rowOff + lane) = o;
}

__device__ __forceinline__ int lower_bound(const int* __restrict__ a, int n, int key) {
    int lo = 0, hi = n;
    while (lo < hi) {
        int mid = (lo + hi) >> 1;
        if (a[mid] < key) lo = mid + 1; else hi = mid;
    }
    return lo;
}

// block per graph; 4 node-parallel groups x 64 lanes x f16x2.
__global__ __launch_bounds__(256) void pool_kernel(const f16* __restrict__ H,
                                                   const int* __restrict__ batch,
                                                   float* __restrict__ pooled, int n) {
    __shared__ float red[3][64][4];
    int g = blockIdx.x;
    int beg = lower_bound(batch, n, g);
    int end = lower_bound(batch, n, g + 1);
    int t = threadIdx.x, sub = t >> 6, lane = t & 63;
    const f16x2* Hv = (const f16x2*)H;
    float sx = 0.f, sy = 0.f, mx = -INFINITY, my = -INFINITY;
    for (int i = beg + sub; i < end; i += 4) {
        f16x2 v = Hv[(size_t)i * 64 + lane];
        float a = (float)v[0], c = (float)v[1];
        sx += a; sy += c;
        mx = fmaxf(mx, a); my = fmaxf(my, c);
    }
    if (sub) {
        red[sub - 1][lane][0] = sx; red[sub - 1][lane][1] = sy;
        red[sub - 1][lane][2] = mx; red[sub - 1][lane][3] = my;
    }
    __syncthreads();
    if (sub == 0) {
#pragma unroll
        for (int k = 0; k < 3; ++k) {
            sx += red[k][lane][0]; sy += red[k][lane][1];
            mx = fmaxf(mx, red[k][lane][2]); my = fmaxf(my, red[k][lane][3]);
        }
        float cnt = fmaxf((float)(end - beg), 1.0f);
        pooled[(size_t)g * 256 + 2 * lane]       = sx / cnt;
        pooled[(size_t)g * 256 + 2 * lane + 1]   = sy / cnt;
        pooled[(size_t)g * 256 + 128 + 2 * lane]     = mx;
        pooled[(size_t)g * 256 + 128 + 2 * lane + 1] = my;
    }
}

__global__ __launch_bounds__(64) void fc_kernel(const float* __restrict__ pooled,
                                                const float* __restrict__ fcW,
                                                const float* __restrict__ fcb,
                                                float* __restrict__ out, int C) {
    int g = blockIdx.x;
    __shared__ float p[256];
    int t = threadIdx.x;
    for (int k = t; k < 256; k += 64) p[k] = pooled[(size_t)g * 256 + k];
    __syncthreads();
    if (t < C) {
        float acc = fcb[t];
        for (int k = 0; k < 256; ++k) acc = fmaf(p[k], fcW[k * C + t], acc);
        out[(size_t)g * C + t] = acc;
    }
}

extern "C" void kernel_launch(void* const* d_in, const int* in_sizes, int n_in,
                              void* d_out, int out_size, void* d_ws, size_t ws_size,
                              hipStream_t stream) {
    const float* x     = (const float*)d_in[0];
    const int*   ei    = (const int*)d_in[1];
    const int*   batch = (const int*)d_in[2];
    const float* W1    = (const float*)d_in[3];
    const float* b1    = (const float*)d_in[4];
    const float* W2    = (const float*)d_in[5];
    const float* b2    = (const float*)d_in[6];
    const float* W3    = (const float*)d_in[7];
    const float* b3    = (const float*)d_in[8];
    const float* fcW   = (const float*)d_in[9];
    const float* fcb   = (const float*)d_in[10];

    const int N = in_sizes[0] / 128;
    const int E = in_sizes[1] / 2;
    const int C = in_sizes[10];
    const int G = out_size / C;
    const int NB = (N + BINSZ - 1) >> BIN_BITS;       // <= 512
    const int chunk = (E + CB - 1) / CB;
    float* out = (float*)d_out;

    // workspace layout
    f16*      Yh      = (f16*)d_ws;                          // [N*128]
    f16*      Ah      = Yh + (size_t)N * 128;                // [N*128]
    f16x8*    wf      = (f16x8*)(Ah + (size_t)N * 128);      // [3*2048]
    float*    dinv    = (float*)(wf + 3 * 2048);             // [N]
    float*    pooled  = dinv + N;                            // [G*256]
    int*      row_ptr = (int*)(pooled + (size_t)G * 256);    // [N+8]
    int*      csr_src = row_ptr + N + 8;                     // [E]
    unsigned* ebuf    = (unsigned*)(csr_src + E);            // [E]
    int*      bcnt    = (int*)(ebuf + E);                    // [256*512]
    int*      tot     = bcnt + 256 * 512;                    // [512]
    int*      base    = tot + 512;                           // [512+8]

    const int* src = ei;
    const int* dst = ei + E;

    // --- deterministic radix CSR build (no global atomics) ---
    prep_count<<<24 + CB, 256, 0, stream>>>(W1, W2, W3, wf, dst, bcnt, E, NB, chunk);
    binscan<<<NB, 256, 0, stream>>>(bcnt, tot, NB);
    s512scan<<<1, 512, 0, stream>>>(tot, base, row_ptr, NB, N, E);
    bucket_place<<<CB, 256, 0, stream>>>(src, dst, base, bcnt, ebuf, E, NB, chunk);
    place_kernel<<<NB, 256, 0, stream>>>(ebuf, base, row_ptr, csr_src, dinv, N);

    const int gemmBlocks = (N + 63) / 64;
    const int aggBlocks = (int)(((long long)N * 64 + 255) / 256);

    gemm_mfma_f<<<gemmBlocks, 256, 0, stream>>>(x, wf, dinv, Yh, N);
    agg_fused<<<aggBlocks, 256, 0, stream>>>(Yh, row_ptr, csr_src, dinv, b1, Ah, N);
    gemm_mfma_h<<<gemmBlocks, 256, 0, stream>>>(Ah, wf + 2048, dinv, Yh, N);
    agg_fused<<<aggBlocks, 256, 0, stream>>>(Yh, row_ptr, csr_src, dinv, b2, Ah, N);
    gemm_mfma_h<<<gemmBlocks, 256, 0, stream>>>(Ah, wf + 4096, dinv, Yh, N);
    agg_fused<<<aggBlocks, 256, 0, stream>>>(Yh, row_ptr, csr_src, dinv, b3, Ah, N);

    pool_kernel<<<G, 256, 0, stream>>>(Ah, batch, pooled, N);
    fc_kernel<<<G, 64, 0, stream>>>(pooled, fcW, fcb, out, C);
}